// Round 9
// baseline (7522.932 us; speedup 1.0000x reference)
//
#include <hip/hip_runtime.h>
#include <hip/hip_bf16.h>

// Problem constants
#define NHEAD 8
#define SLEN 64
#define TLEN 32
#define NNODE 512
#define NEDGE 16384
#define NLAYER 4

typedef __attribute__((ext_vector_type(8))) __bf16 bf16x8;
typedef __attribute__((ext_vector_type(4))) __bf16 bf16x4;
typedef __attribute__((ext_vector_type(4))) float  f32x4;

// ---------------------------------------------------------------------------
// async global->LDS 16B (wave-uniform LDS base + lane*16 semantics)
// ---------------------------------------------------------------------------
__device__ __forceinline__ void gload16(const void* g, void* l)
{
    __builtin_amdgcn_global_load_lds(
        (const __attribute__((address_space(1))) void*)g,
        (__attribute__((address_space(3))) void*)l, 16, 0, 0);
}

// ---------------------------------------------------------------------------
// bf16 GEMM (m97 structure): A[M][K] bf16, Bt[N][K] bf16 (pre-transposed),
// C = A@B + bias.  outMode: 0=f32, 1=f32+relu, 2=bf16+relu, 3=bf16.
// BM=128, BN template {128,64}. 256 thr = 4 waves:
//   BN=128: 2x2 waves, wave tile 64x64, acc 4x4
//   BN=64 : 4x1 waves, wave tile 32x64, acc 2x4  (for N=512 small-M GEMMs ->
//           2x the blocks/CU so barrier drains overlap across blocks)
// global_load_lds width-16 staging into linear LDS [row][64].
// M%128==0, N%BN==0, K%64==0.
// ---------------------------------------------------------------------------
template<int BN>
__global__ __launch_bounds__(256) void gemm_bf16(
    const __bf16* __restrict__ A, int lda,
    const __bf16* __restrict__ Bt, int ldb,
    const float* __restrict__ bias,
    float* __restrict__ Cf, __bf16* __restrict__ Cb, int ldc,
    int M, int N, int K, int outMode)
{
    constexpr int FM = (BN == 128) ? 4 : 2;   // A-fragments per wave
    __shared__ __bf16 As[128 * 64];
    __shared__ __bf16 Bs[BN * 64];
    const int tid  = threadIdx.x;
    const int wid  = tid >> 6;
    const int lane = tid & 63;
    const int wr = (BN == 128) ? (wid >> 1) : wid;
    const int wc = (BN == 128) ? (wid & 1) : 0;
    const int m0 = blockIdx.y * 128, n0 = blockIdx.x * BN;

    const int srow = wid * 8 + (lane >> 3);   // staging row within 32-group
    const int scol = (lane & 7) * 8;          // staging col (bf16 elems)
    const int lr = lane & 15;
    const int kg = (lane >> 4) * 8;

    f32x4 acc[FM][4];
    #pragma unroll
    for (int m = 0; m < FM; ++m)
        #pragma unroll
        for (int n = 0; n < 4; ++n)
            acc[m][n] = (f32x4){0.0f, 0.0f, 0.0f, 0.0f};

    for (int k0 = 0; k0 < K; k0 += 64) {
        #pragma unroll
        for (int g = 0; g < 4; ++g) {
            const __bf16* ga = A + (size_t)(m0 + g * 32 + srow) * lda + k0 + scol;
            gload16(ga, &As[(g * 32 + wid * 8) * 64]);
        }
        #pragma unroll
        for (int g = 0; g < BN / 32; ++g) {
            const __bf16* gb = Bt + (size_t)(n0 + g * 32 + srow) * ldb + k0 + scol;
            gload16(gb, &Bs[(g * 32 + wid * 8) * 64]);
        }
        __syncthreads();
        #pragma unroll
        for (int kk = 0; kk < 64; kk += 32) {
            bf16x8 fa[FM], fb[4];
            #pragma unroll
            for (int m = 0; m < FM; ++m)
                fa[m] = *reinterpret_cast<const bf16x8*>(
                    &As[(wr * (16 * FM) + m * 16 + lr) * 64 + kk + kg]);
            #pragma unroll
            for (int n = 0; n < 4; ++n)
                fb[n] = *reinterpret_cast<const bf16x8*>(
                    &Bs[(wc * 64 + n * 16 + lr) * 64 + kk + kg]);
            #pragma unroll
            for (int m = 0; m < FM; ++m)
                #pragma unroll
                for (int n = 0; n < 4; ++n)
                    acc[m][n] = __builtin_amdgcn_mfma_f32_16x16x32_bf16(
                        fa[m], fb[n], acc[m][n], 0, 0, 0);
        }
        __syncthreads();
    }

    const int cr = (lane >> 4) * 4;
    const int cc = lane & 15;
    #pragma unroll
    for (int n = 0; n < 4; ++n) {
        const int gcol = n0 + wc * 64 + n * 16 + cc;
        const float bb = bias[gcol];
        #pragma unroll
        for (int m = 0; m < FM; ++m) {
            #pragma unroll
            for (int j = 0; j < 4; ++j) {
                const int grow = m0 + wr * (16 * FM) + m * 16 + cr + j;
                float v = acc[m][n][j] + bb;
                if (outMode == 1 || outMode == 2) v = fmaxf(v, 0.0f);
                if (outMode >= 2) Cb[(size_t)grow * ldc + gcol] = (__bf16)v;
                else              Cf[(size_t)grow * ldc + gcol] = v;
            }
        }
    }
}

// ---------------------------------------------------------------------------
// fp32 GEMM (input proj, w_map, GAT g1/g2)
// ---------------------------------------------------------------------------
__global__ __launch_bounds__(256) void gemm_bias(
    const float* __restrict__ A, int lda,
    const float* __restrict__ B, int ldb,
    const float* __restrict__ bias,
    float* __restrict__ C, int ldc,
    int M, int N, int K, int relu)
{
    __shared__ float As[16][68];
    __shared__ float Bs[16][68];
    const int tid = threadIdx.x;
    const int tx = tid & 15, ty = tid >> 4;
    const int m0 = blockIdx.y * 64, n0 = blockIdx.x * 64;
    const int liA_m = tid >> 2;
    const int liA_k = (tid & 3) * 4;
    const int liB_n = (tid & 15) * 4;
    const int liB_k = tid >> 4;
    float acc[4][4] = {};
    for (int k0 = 0; k0 < K; k0 += 16) {
        float4 av = *reinterpret_cast<const float4*>(&A[(size_t)(m0 + liA_m) * lda + k0 + liA_k]);
        float4 bv = *reinterpret_cast<const float4*>(&B[(size_t)(k0 + liB_k) * ldb + n0 + liB_n]);
        As[liA_k + 0][liA_m] = av.x;
        As[liA_k + 1][liA_m] = av.y;
        As[liA_k + 2][liA_m] = av.z;
        As[liA_k + 3][liA_m] = av.w;
        *reinterpret_cast<float4*>(&Bs[liB_k][liB_n]) = bv;
        __syncthreads();
        #pragma unroll
        for (int kk = 0; kk < 16; ++kk) {
            float4 a4 = *reinterpret_cast<const float4*>(&As[kk][ty * 4]);
            float4 b4 = *reinterpret_cast<const float4*>(&Bs[kk][tx * 4]);
            float a[4] = {a4.x, a4.y, a4.z, a4.w};
            float b[4] = {b4.x, b4.y, b4.z, b4.w};
            #pragma unroll
            for (int i = 0; i < 4; ++i)
                #pragma unroll
                for (int j = 0; j < 4; ++j)
                    acc[i][j] += a[i] * b[j];
        }
        __syncthreads();
    }
    #pragma unroll
    for (int i = 0; i < 4; ++i) {
        const int m = m0 + ty * 4 + i;
        #pragma unroll
        for (int j = 0; j < 4; ++j) {
            const int n = n0 + tx * 4 + j;
            float v = acc[i][j] + bias[n];
            if (relu) v = fmaxf(v, 0.0f);
            C[(size_t)m * ldc + n] = v;
        }
    }
}

// ---------------------------------------------------------------------------
// Tiled transpose + fp32->bf16: in [L][K][N] -> out [L][N][K] (L = gridDim.z)
// ---------------------------------------------------------------------------
__global__ __launch_bounds__(256) void transpose_w(
    const float* __restrict__ in, __bf16* __restrict__ out, int K, int N)
{
    __shared__ __bf16 t[32][33];
    const int l = blockIdx.z;
    in  += (size_t)l * K * N;
    out += (size_t)l * K * N;
    const int k0 = blockIdx.y * 32, n0 = blockIdx.x * 32;
    const int tx = threadIdx.x & 31, ty = threadIdx.x >> 5;   // 32 x 8
    #pragma unroll
    for (int i = 0; i < 32; i += 8)
        t[ty + i][tx] = (__bf16)in[(size_t)(k0 + ty + i) * N + n0 + tx];
    __syncthreads();
    #pragma unroll
    for (int i = 0; i < 32; i += 8)
        out[(size_t)(n0 + ty + i) * K + k0 + tx] = t[tx][ty + i];
}

// ---------------------------------------------------------------------------
__global__ __launch_bounds__(256) void conv_bf16(
    const float* __restrict__ in, __bf16* __restrict__ out, int total4)
{
    const int i = blockIdx.x * 256 + threadIdx.x;
    if (i >= total4) return;
    const float4 v = *reinterpret_cast<const float4*>(&in[(size_t)i * 4]);
    bf16x4 w;
    w[0] = (__bf16)v.x; w[1] = (__bf16)v.y; w[2] = (__bf16)v.z; w[3] = (__bf16)v.w;
    *reinterpret_cast<bf16x4*>(&out[(size_t)i * 4]) = w;
}

// ---------------------------------------------------------------------------
__global__ __launch_bounds__(256) void permute_in(
    const float* __restrict__ in, float* __restrict__ out, int L, int CH, int total)
{
    const int idx = blockIdx.x * 256 + threadIdx.x;
    if (idx >= total) return;
    const int c = idx % CH;
    const int r = idx / CH;       // r = l*512 + n
    const int n = r & 511;
    const int l = r >> 9;
    out[((size_t)n * L + l) * CH + c] = in[idx];
}

// ---------------------------------------------------------------------------
// Fused MHA, bf16 in/out, node-major within chunk. One wave per (n,h).
// ---------------------------------------------------------------------------
template<int LQ, int LK, bool CAUSAL>
__global__ __launch_bounds__(64) void attn_bf16(
    const __bf16* __restrict__ Q, int ldq,
    const __bf16* __restrict__ Kp, int ldk,
    const __bf16* __restrict__ Vp, int ldv,
    __bf16* __restrict__ O, int ldo)
{
    __shared__ float qs[LQ][68];
    __shared__ float ks[LK][68];
    __shared__ float vs[LK][68];
    const int n = blockIdx.x >> 3;
    const int h = blockIdx.x & 7;
    const int lane = threadIdx.x;
    const int col = h * 64 + lane;
    for (int r = 0; r < LQ; ++r) qs[r][lane] = (float)Q[(size_t)(n * LQ + r) * ldq + col];
    for (int r = 0; r < LK; ++r) ks[r][lane] = (float)Kp[(size_t)(n * LK + r) * ldk + col];
    for (int r = 0; r < LK; ++r) vs[r][lane] = (float)Vp[(size_t)(n * LK + r) * ldv + col];
    __syncthreads();
    float o[64];
    if (lane < LQ) {
        float qr[64];
        #pragma unroll
        for (int j = 0; j < 64; ++j) { qr[j] = qs[lane][j]; o[j] = 0.0f; }
        float m = -1e30f, l = 0.0f;
        const int kend = CAUSAL ? (lane + 1) : LK;
        for (int kk = 0; kk < kend; ++kk) {
            float s = 0.0f;
            #pragma unroll
            for (int j = 0; j < 16; ++j) {
                float4 kv = *reinterpret_cast<const float4*>(&ks[kk][j * 4]);
                s += qr[4*j+0]*kv.x + qr[4*j+1]*kv.y + qr[4*j+2]*kv.z + qr[4*j+3]*kv.w;
            }
            s *= 0.125f;
            const float mn = fmaxf(m, s);
            const float sc = expf(m - mn);
            const float p  = expf(s - mn);
            l = l * sc + p;
            #pragma unroll
            for (int j = 0; j < 16; ++j) {
                float4 vv = *reinterpret_cast<const float4*>(&vs[kk][j * 4]);
                o[4*j+0] = o[4*j+0] * sc + p * vv.x;
                o[4*j+1] = o[4*j+1] * sc + p * vv.y;
                o[4*j+2] = o[4*j+2] * sc + p * vv.z;
                o[4*j+3] = o[4*j+3] * sc + p * vv.w;
            }
            m = mn;
        }
        const float inv = 1.0f / l;
        #pragma unroll
        for (int j = 0; j < 64; ++j) o[j] *= inv;
    }
    __syncthreads();
    if (lane < LQ) {
        #pragma unroll
        for (int j = 0; j < 64; ++j) qs[lane][j] = o[j];
    }
    __syncthreads();
    for (int r = 0; r < LQ; ++r)
        O[(size_t)(n * LQ + r) * ldo + col] = (__bf16)qs[r][lane];
}

// ---------------------------------------------------------------------------
// LayerNorm(512) bf16: out = LN(x [+ d]) * g + b, fp32 math.
// ---------------------------------------------------------------------------
template<bool HASR, bool F32OUT>
__global__ __launch_bounds__(256) void ln_bf16(
    const __bf16* __restrict__ X, const __bf16* __restrict__ Rb,
    const float* __restrict__ g, const float* __restrict__ b,
    __bf16* __restrict__ outb, float* __restrict__ outf, int ntok)
{
    const int wid = threadIdx.x >> 6, lane = threadIdx.x & 63;
    const int row = blockIdx.x * 4 + wid;
    if (row >= ntok) return;
    const size_t base = (size_t)row * 512;
    float v[8];
    float s = 0.0f;
    #pragma unroll
    for (int j = 0; j < 8; ++j) {
        float t = (float)X[base + j * 64 + lane];
        if (HASR) t += (float)Rb[base + j * 64 + lane];
        v[j] = t; s += t;
    }
    #pragma unroll
    for (int d = 32; d >= 1; d >>= 1) s += __shfl_xor(s, d, 64);
    const float mean = s * (1.0f / 512.0f);
    float vs = 0.0f;
    #pragma unroll
    for (int j = 0; j < 8; ++j) { const float d = v[j] - mean; vs += d * d; }
    #pragma unroll
    for (int d = 32; d >= 1; d >>= 1) vs += __shfl_xor(vs, d, 64);
    const float rstd = rsqrtf(vs * (1.0f / 512.0f) + 1e-5f);
    #pragma unroll
    for (int j = 0; j < 8; ++j) {
        const int c = j * 64 + lane;
        const float val = (v[j] - mean) * rstd * g[c] + b[c];
        if (F32OUT) outf[base + c] = val;
        else        outb[base + c] = (__bf16)val;
    }
}

// ---------------------------------------------------------------------------
__global__ __launch_bounds__(256) void add_posenc(float* __restrict__ x, int L, int total)
{
    const int idx = blockIdx.x * 256 + threadIdx.x;
    if (idx >= total) return;
    const int d = idx & 511;
    const int row = idx >> 9;
    const int l = row % L;
    const int i2 = d & ~1;
    const float freq = expf(-9.210340371976184f * (float)i2 / 512.0f);
    const float a = (float)l * freq;
    x[idx] += (d & 1) ? cosf(a) : sinf(a);
}

// ---------------------------------------------------------------------------
__global__ void zero_ints(int* __restrict__ p, int n)
{
    const int i = blockIdx.x * 256 + threadIdx.x;
    if (i < n) p[i] = 0;
}

__global__ void count_deg(const int* __restrict__ edst, int* __restrict__ deg)
{
    const int e = blockIdx.x * 256 + threadIdx.x;
    if (e < NEDGE) atomicAdd(&deg[edst[e]], 1);
}

__global__ void scan512(const int* __restrict__ deg, int* __restrict__ off)
{
    __shared__ int s[512];
    const int tid = threadIdx.x;
    s[tid] = deg[tid];
    __syncthreads();
    for (int d = 1; d < 512; d <<= 1) {
        const int t = (tid >= d) ? s[tid - d] : 0;
        __syncthreads();
        s[tid] += t;
        __syncthreads();
    }
    off[tid + 1] = s[tid];
    if (tid == 0) off[0] = 0;
}

__global__ void fill_eid(const int* __restrict__ edst, const int* __restrict__ off,
                         int* __restrict__ cur, int* __restrict__ eid)
{
    const int e = blockIdx.x * 256 + threadIdx.x;
    if (e < NEDGE) {
        const int d = edst[e];
        const int pos = off[d] + atomicAdd(&cur[d], 1);
        eid[pos] = e;
    }
}

// ---------------------------------------------------------------------------
// GATv2, two-pass per 128-edge tile: pass1 computes all scores into LDS (only
// a fmax in the loop-carried chain), pass2 does one exp per edge + den/acc.
// Math is the same values as online-softmax, different association (tolerance
// is ample). xl gather re-read in pass2 (L2-hot).
// ---------------------------------------------------------------------------
template<bool FINAL>
__global__ __launch_bounds__(256) void gatv2_kernel(
    const float* __restrict__ xl, const float* __restrict__ xr,
    const float* __restrict__ att, const float* __restrict__ bias,
    const int* __restrict__ off, const int* __restrict__ eid,
    const int* __restrict__ esrc,
    float* __restrict__ outf, float* __restrict__ outd)
{
    __shared__ float wsc[128][8];     // score per (tile-edge, head): 4 KB
    const int blk = blockIdx.x;       // t*NNODE + i
    const int i = blk & (NNODE - 1);
    const int t = blk >> 9;
    const int tid = threadIdx.x;
    const int head = tid >> 5;
    const int lane32 = tid & 31;
    const float xrv = xr[((size_t)i * TLEN + t) * 256 + tid];
    const float av = att[tid];
    const int e0 = off[i], e1 = off[i + 1];
    float m = -1e30f, den = 0.0f, acc = 0.0f;
    for (int base = e0; base < e1; base += 128) {
        const int te = min(128, e1 - base);
        // ---- pass 1: scores -> LDS, tile max ----
        float tm = -1e30f;
        for (int k = 0; k < te; ++k) {
            const int s = esrc[eid[base + k]];
            const float xlv = xl[((size_t)s * TLEN + t) * 256 + tid];
            float z = xlv + xrv;
            z = (z > 0.0f) ? z : 0.2f * z;      // leaky_relu(0.2)
            float w = z * av;
            #pragma unroll
            for (int d = 16; d >= 1; d >>= 1) w += __shfl_xor(w, d, 32);
            if (lane32 == 0) wsc[k][head] = w;
            tm = fmaxf(tm, w);
        }
        // ---- merge running max (rescale once per tile) ----
        const float mn = fmaxf(m, tm);
        const float sc = expf(m - mn);          // 0 on first tile (m=-1e30)
        den *= sc; acc *= sc; m = mn;
        // ---- pass 2: one exp per edge, accumulate ----
        for (int k = 0; k < te; ++k) {
            const float w = wsc[k][head];
            const float p = expf(w - m);
            const int s = esrc[eid[base + k]];
            const float xlv = xl[((size_t)s * TLEN + t) * 256 + tid];
            den += p;
            acc += p * xlv;
        }
    }
    float o = (den > 0.0f) ? acc / den : 0.0f;
    o += bias[tid];
    if (FINAL) {
        o = fmaxf(o, 0.0f);
        outd[(size_t)blk * 256 + tid] = o;
    } else {
        outf[((size_t)i * TLEN + t) * 256 + tid] = o;
    }
}

// ---------------------------------------------------------------------------
extern "C" void kernel_launch(void* const* d_in, const int* in_sizes, int n_in,
                              void* d_out, int out_size, void* d_ws, size_t ws_size,
                              hipStream_t stream)
{
    const float* src       = (const float*)d_in[0];
    const float* tgt       = (const float*)d_in[1];
    const float* w_enc_in  = (const float*)d_in[2];
    const float* b_enc_in  = (const float*)d_in[3];
    const float* w_dec_in  = (const float*)d_in[4];
    const float* b_dec_in  = (const float*)d_in[5];
    const float* w_map     = (const float*)d_in[6];
    const float* b_map     = (const float*)d_in[7];
    const float* enc_qkv_w = (const float*)d_in[8];
    const float* enc_qkv_b = (const float*)d_in[9];
    const float* enc_out_w = (const float*)d_in[10];
    const float* enc_out_b = (const float*)d_in[11];
    const float* enc_ff1_w = (const float*)d_in[12];
    const float* enc_ff1_b = (const float*)d_in[13];
    const float* enc_ff2_w = (const float*)d_in[14];
    const float* enc_ff2_b = (const float*)d_in[15];
    const float* enc_ln1_g = (const float*)d_in[16];
    const float* enc_ln1_b = (const float*)d_in[17];
    const float* enc_ln2_g = (const float*)d_in[18];
    const float* enc_ln2_b = (const float*)d_in[19];
    const float* enc_fn_g  = (const float*)d_in[20];
    const float* enc_fn_b  = (const float*)d_in[21];
    const float* dec_sa_qkv_w = (const float*)d_in[22];
    const float* dec_sa_qkv_b = (const float*)d_in[23];
    const float* dec_sa_out_w = (const float*)d_in[24];
    const float* dec_sa_out_b = (const float*)d_in[25];
    const float* dec_ca_qkv_w = (const float*)d_in[26];
    const float* dec_ca_qkv_b = (const float*)d_in[27];
    const float* dec_ca_out_w = (const float*)d_in[28];
    const float* dec_ca_out_b = (const float*)d_in[29];
    const float* dec_ff1_w = (const float*)d_in[30];
    const float* dec_ff1_b = (const float*)d_in[31];
    const float* dec_ff2_w = (const float*)d_in[32];
    const float* dec_ff2_b = (const float*)d_in[33];
    const float* dec_ln1_g = (const float*)d_in[34];
    const float* dec_ln1_b = (const float*)d_in[35];
    const float* dec_ln2_g = (const float*)d_in[36];
    const float* dec_ln2_b = (const float*)d_in[37];
    const float* dec_ln3_g = (const float*)d_in[38];
    const float* dec_ln3_b = (const float*)d_in[39];
    const float* dec_fn_g  = (const float*)d_in[40];
    const float* dec_fn_b  = (const float*)d_in[41];
    const float* g1_wl   = (const float*)d_in[42];
    const float* g1_wr   = (const float*)d_in[43];
    const float* g1_bl   = (const float*)d_in[44];
    const float* g1_br   = (const float*)d_in[45];
    const float* g1_att  = (const float*)d_in[46];
    const float* g1_bias = (const float*)d_in[47];
    const float* g2_wl   = (const float*)d_in[48];
    const float* g2_wr   = (const float*)d_in[49];
    const float* g2_bl   = (const float*)d_in[50];
    const float* g2_br   = (const float*)d_in[51];
    const float* g2_att  = (const float*)d_in[52];
    const float* g2_bias = (const float*)d_in[53];
    const int*   edge_index = (const int*)d_in[54];
    const int* esrc = edge_index;
    const int* edst = edge_index + NEDGE;

    // ---- lean full-batch layout (floats; total ~149 MiB) ----
    float* wsf = (float*)d_ws;
    __bf16* Xb = (__bf16*)wsf;                          // 32768x512 bf16 (8,388,608 f)
    __bf16* Yb = (__bf16*)(wsf + 8388608);              // 16384x512 bf16 (4,194,304 f)
    float*  Rf = wsf + 12582912;                        // R region: 8,388,608 f
    float*  Mf = wsf + 20971520;                        // M region: 8,388,608 f
    float*  Wf = wsf + 29360128;                        // W region: 8,388,608 f
    float*  F  = wsf + 37748736;                        // 1,048,576 f
    int* ipool = (int*)(wsf + 38797312);
    int* deg = ipool;
    int* off = deg + 512;
    int* cur = off + 516;
    int* eid = cur + 512;
    __bf16* Rb16 = (__bf16*)Rf;
    __bf16* Mb16 = (__bf16*)Mf;
    __bf16* Wb   = (__bf16*)Wf;

    auto gemm = [&](const float* A, int lda, const float* B, int ldb, const float* bias,
                    float* Cc, int ldc, int M, int N, int K, int relu) {
        dim3 grid((unsigned)(N / 64), (unsigned)(M / 64));
        gemm_bias<<<grid, 256, 0, stream>>>(A, lda, B, ldb, bias, Cc, ldc, M, N, K, relu);
    };
    auto gemmT = [&](const __bf16* A, int lda, const __bf16* Bt, int ldb,
                     const float* bias, float* Cf, __bf16* Cb, int ldc,
                     int M, int N, int K, int mode) {
        dim3 grid((unsigned)(N / 128), (unsigned)(M / 128));
        gemm_bf16<128><<<grid, 256, 0, stream>>>(A, lda, Bt, ldb, bias, Cf, Cb, ldc, M, N, K, mode);
    };
    auto gemmT64 = [&](const __bf16* A, int lda, const __bf16* Bt, int ldb,
                       const float* bias, float* Cf, __bf16* Cb, int ldc,
                       int M, int N, int K, int mode) {
        dim3 grid((unsigned)(N / 64), (unsigned)(M / 128));
        gemm_bf16<64><<<grid, 256, 0, stream>>>(A, lda, Bt, ldb, bias, Cf, Cb, ldc, M, N, K, mode);
    };
    auto tw = [&](const float* w, __bf16* o, int K, int N) {
        dim3 g((unsigned)(N / 32), (unsigned)(K / 32), NLAYER);
        transpose_w<<<g, 256, 0, stream>>>(w, o, K, N);
    };

    // ---- CSR build ----
    zero_ints<<<8, 256, 0, stream>>>(ipool, 512 + 516 + 512);
    count_deg<<<NEDGE / 256, 256, 0, stream>>>(edst, deg);
    scan512<<<1, 512, 0, stream>>>(deg, off);
    fill_eid<<<NEDGE / 256, 256, 0, stream>>>(edst, off, cur, eid);

    // ---- input permute + fp32 projections + posenc + convert to bf16 ----
    {
        float* src_nm = Wf;                     // 1,048,576 f
        float* Xtmp = Rf;                       // 16,777,216 f spans R+M
        permute_in<<<4096, 256, 0, stream>>>(src, src_nm, SLEN, 32, 32768 * 32);
        gemm(src_nm, 32, w_enc_in, 512, b_enc_in, Xtmp, 512, 32768, 512, 32, 0);
        add_posenc<<<(32768 * 512) / 256, 256, 0, stream>>>(Xtmp, SLEN, 32768 * 512);
        conv_bf16<<<16384, 256, 0, stream>>>(Xtmp, Xb, 32768 * 128);
        float* tgt_nm = Wf;
        float* Ytmp = Rf;                       // 8,388,608 f in R
        permute_in<<<4096, 256, 0, stream>>>(tgt, tgt_nm, TLEN, 64, 16384 * 64);
        gemm(tgt_nm, 64, w_dec_in, 512, b_dec_in, Ytmp, 512, 16384, 512, 64, 0);
        add_posenc<<<(16384 * 512) / 256, 256, 0, stream>>>(Ytmp, TLEN, 16384 * 512);
        conv_bf16<<<8192, 256, 0, stream>>>(Ytmp, Yb, 16384 * 128);
    }

    // ---- encoder weights -> W (bf16, transposed) ----
    __bf16* WeQkv = Wb + 0;          // [4][1536][512]
    __bf16* WeOut = Wb + 3145728;    // [4][512][512]
    __bf16* WeFf1 = Wb + 4194304;    // [4][2048][512]
    __bf16* WeFf2 = Wb + 8388608;    // [4][512][2048]
    tw(enc_qkv_w, WeQkv, 512, 1536);
    tw(enc_out_w, WeOut, 512, 512);
    tw(enc_ff1_w, WeFf1, 512, 2048);
    tw(enc_ff2_w, WeFf2, 2048, 512);

    // ================= encoder (full batch, 32768 rows) =================
    for (int i = 0; i < NLAYER; ++i) {
        // QKV + attention, 4 chunks of 128 nodes (8192 rows)
        for (int c = 0; c < 4; ++c) {
            gemmT(Xb + (size_t)c * 8192 * 512, 512, WeQkv + (size_t)i * 786432, 512,
                  enc_qkv_b + (size_t)i * 1536, nullptr, Rb16, 1536, 8192, 1536, 512, 3);
            attn_bf16<64, 64, false><<<1024, 64, 0, stream>>>(
                Rb16, 1536, Rb16 + 512, 1536, Rb16 + 1024, 1536,
                Mb16 + (size_t)c * 8192 * 512, 512);
        }
        // attn output projection (full batch, 1024 blocks) -> delta in R
        gemmT(Mb16, 512, WeOut + (size_t)i * 262144, 512, enc_out_b + (size_t)i * 512,
              nullptr, Rb16, 512, 32768, 512, 512, 3);
        ln_bf16<true, false><<<8192, 256, 0, stream>>>(Xb, Rb16,
            enc_ln1_g + (size_t)i * 512, enc_ln1_b + (size_t)i * 512, Xb, nullptr, 32768);
        // FFN, 4 chunks of 8192 rows (mid bf16 8192x2048 = M region)
        for (int s = 0; s < 4; ++s) {
            gemmT(Xb + (size_t)s * 8192 * 512, 512, WeFf1 + (size_t)i * 1048576, 512,
                  enc_ff1_b + (size_t)i * 2048, nullptr, Mb16, 2048, 8192, 2048, 512, 2);
            gemmT64(Mb16, 2048, WeFf2 + (size_t)i * 1048576, 2048,
                    enc_ff2_b + (size_t)i * 512, nullptr, Rb16 + (size_t)s * 8192 * 512, 512,
                    8192, 512, 2048, 3);
        }
        ln_bf16<true, false><<<8192, 256, 0, stream>>>(Xb, Rb16,
            enc_ln2_g + (size_t)i * 512, enc_ln2_b + (size_t)i * 512, Xb, nullptr, 32768);
    }
    ln_bf16<false, false><<<8192, 256, 0, stream>>>(Xb, nullptr, enc_fn_g, enc_fn_b,
                                                    Xb, nullptr, 32768);
    // Xb is now MEMb

    // ---- decoder weights -> W (overwrites encoder set) ----
    __bf16* WdSaQkv = Wb + 0;          // [4][1536][512]
    __bf16* WdSaOut = Wb + 3145728;    // [4][512][512]
    __bf16* WdCaQkv = Wb + 4194304;    // [4][1536][512]
    __bf16* WdCaOut = Wb + 7340032;    // [4][512][512]
    __bf16* WdFf1   = Wb + 8388608;    // [4][2048][512]
    __bf16* WdFf2   = Wb + 12582912;   // [4][512][2048]
    tw(dec_sa_qkv_w, WdSaQkv, 512, 1536);
    tw(dec_sa_out_w, WdSaOut, 512, 512);
    tw(dec_ca_qkv_w, WdCaQkv, 512, 1536);
    tw(dec_ca_out_w, WdCaOut, 512, 512);
    tw(dec_ff1_w,    WdFf1,   512, 2048);
    tw(dec_ff2_w,    WdFf2,   2048, 512);

    // ================= decoder (full batch, 16384 rows) =================
    __bf16* ObD  = Mb16;                       // 16384x512 bf16
    __bf16* QbC  = Mb16;                       // 8192x512 bf16 chunk
    __bf16* ObCA = (__bf16*)(Mf + 2097152);    // 16384x512 bf16
    for (int i = 0; i < NLAYER; ++i) {
        // causal self-attention, 2 chunks of 256 nodes (8192 rows)
        for (int c = 0; c < 2; ++c) {
            gemmT(Yb + (size_t)c * 8192 * 512, 512, WdSaQkv + (size_t)i * 786432, 512,
                  dec_sa_qkv_b + (size_t)i * 1536, nullptr, Rb16, 1536, 8192, 1536, 512, 3);
            attn_bf16<32, 32, true><<<2048, 64, 0, stream>>>(
                Rb16, 1536, Rb16 + 512, 1536, Rb16 + 1024, 1536,
                ObD + (size_t)c * 8192 * 512, 512);
        }
        gemmT64(ObD, 512, WdSaOut + (size_t)i * 262144, 512, dec_sa_out_b + (size_t)i * 512,
                nullptr, Rb16, 512, 16384, 512, 512, 3);
        ln_bf16<true, false><<<4096, 256, 0, stream>>>(Yb, Rb16,
            dec_ln1_g + (size_t)i * 512, dec_ln1_b + (size_t)i * 512, Yb, nullptr, 16384);
        // cross-attention, 2 chunks of 256 nodes (Q 8192 rows, KV 16384 rows)
        for (int c = 0; c < 2; ++c) {
            gemmT64(Yb + (size_t)c * 8192 * 512, 512, WdCaQkv + (size_t)i * 786432, 512,
                    dec_ca_qkv_b + (size_t)i * 1536, nullptr, QbC, 512, 8192, 512, 512, 3);
            gemmT(Xb + (size_t)c * 16384 * 512, 512, WdCaQkv + (size_t)i * 786432 + 262144, 512,
                  dec_ca_qkv_b + (size_t)i * 1536 + 512, nullptr, Rb16, 1024, 16384, 1024, 512, 3);
            attn_bf16<32, 64, false><<<2048, 64, 0, stream>>>(
                QbC, 512, Rb16, 1024, Rb16 + 512, 1024,
                ObCA + (size_t)c * 8192 * 512, 512);
        }
        gemmT64(ObCA, 512, WdCaOut + (size_t)i * 262144, 512, dec_ca_out_b + (size_t)i * 512,
                nullptr, Rb16, 512, 16384, 512, 512, 3);
        ln_bf16<true, false><<<4096, 256, 0, stream>>>(Yb, Rb16,
            dec_ln2_g + (size_t)i * 512, dec_ln2_b + (size_t)i * 512, Yb, nullptr, 16384);
        // FFN, 2 chunks of 8192 rows
        for (int s = 0; s < 2; ++s) {
            gemmT(Yb + (size_t)s * 8192 * 512, 512, WdFf1 + (size_t)i * 1048576, 512,
                  dec_ff1_b + (size_t)i * 2048, nullptr, Mb16, 2048, 8192, 2048, 512, 2);
            gemmT64(Mb16, 2048, WdFf2 + (size_t)i * 1048576, 2048,
                    dec_ff2_b + (size_t)i * 512, nullptr, Rb16 + (size_t)s * 8192 * 512, 512,
                    8192, 512, 2048, 3);
        }
        ln_bf16<true, false><<<4096, 256, 0, stream>>>(Yb, Rb16,
            dec_ln3_g + (size_t)i * 512, dec_ln3_b + (size_t)i * 512, Yb, nullptr, 16384);
    }
    // final decoder LN -> fp32 in R
    float* Yf = Rf;
    ln_bf16<false, true><<<4096, 256, 0, stream>>>(Yb, nullptr, dec_fn_g, dec_fn_b,
                                                   nullptr, Yf, 16384);

    // map to FEAT=64
    gemm(Yf, 512, w_map, 64, b_map, F, 64, 16384, 64, 512, 0);

    // ================= spatial GATv2 (fp32) =================
    float* G  = Mf;                 // 4,194,304 f
    float* Hb = Mf + 4194304;       // 4,194,304 f
    float* Ib = Wf;                 // 4,194,304 f (W dead)
    gemm(F, 64, g1_wl, 256, g1_bl, G,  256, 16384, 256, 64, 0);
    gemm(F, 64, g1_wr, 256, g1_br, Hb, 256, 16384, 256, 64, 0);
    gatv2_kernel<false><<<16384, 256, 0, stream>>>(G, Hb, g1_att, g1_bias, off, eid, esrc, Ib, nullptr);
    gemm(Ib, 256, g2_wl, 256, g2_bl, G,  256, 16384, 256, 256, 0);
    gemm(Ib, 256, g2_wr, 256, g2_br, Hb, 256, 16384, 256, 256, 0);
    gatv2_kernel<true><<<16384, 256, 0, stream>>>(G, Hb, g2_att, g2_bias, off, eid, esrc,
                                                  nullptr, (float*)d_out);
}

// Round 10
// 4742.784 us; speedup vs baseline: 1.5862x; 1.5862x over previous
//
#include <hip/hip_runtime.h>
#include <hip/hip_bf16.h>

// Problem constants
#define NHEAD 8
#define SLEN 64
#define TLEN 32
#define NNODE 512
#define NEDGE 16384
#define NLAYER 4

typedef __attribute__((ext_vector_type(8))) __bf16 bf16x8;
typedef __attribute__((ext_vector_type(4))) __bf16 bf16x4;
typedef __attribute__((ext_vector_type(4))) float  f32x4;

// ---------------------------------------------------------------------------
// async global->LDS 16B (wave-uniform LDS base + lane*16 semantics)
// ---------------------------------------------------------------------------
__device__ __forceinline__ void gload16(const void* g, void* l)
{
    __builtin_amdgcn_global_load_lds(
        (const __attribute__((address_space(1))) void*)g,
        (__attribute__((address_space(3))) void*)l, 16, 0, 0);
}

// ---------------------------------------------------------------------------
// bf16 GEMM (m97 structure): A[M][K] bf16, Bt[N][K] bf16 (pre-transposed),
// C = A@B + bias.  outMode: 0=f32, 1=f32+relu, 2=bf16+relu, 3=bf16.
// BM=128, BN template {128,64}.
// ---------------------------------------------------------------------------
template<int BN>
__global__ __launch_bounds__(256) void gemm_bf16(
    const __bf16* __restrict__ A, int lda,
    const __bf16* __restrict__ Bt, int ldb,
    const float* __restrict__ bias,
    float* __restrict__ Cf, __bf16* __restrict__ Cb, int ldc,
    int M, int N, int K, int outMode)
{
    constexpr int FM = (BN == 128) ? 4 : 2;
    __shared__ __bf16 As[128 * 64];
    __shared__ __bf16 Bs[BN * 64];
    const int tid  = threadIdx.x;
    const int wid  = tid >> 6;
    const int lane = tid & 63;
    const int wr = (BN == 128) ? (wid >> 1) : wid;
    const int wc = (BN == 128) ? (wid & 1) : 0;
    const int m0 = blockIdx.y * 128, n0 = blockIdx.x * BN;

    const int srow = wid * 8 + (lane >> 3);
    const int scol = (lane & 7) * 8;
    const int lr = lane & 15;
    const int kg = (lane >> 4) * 8;

    f32x4 acc[FM][4];
    #pragma unroll
    for (int m = 0; m < FM; ++m)
        #pragma unroll
        for (int n = 0; n < 4; ++n)
            acc[m][n] = (f32x4){0.0f, 0.0f, 0.0f, 0.0f};

    for (int k0 = 0; k0 < K; k0 += 64) {
        #pragma unroll
        for (int g = 0; g < 4; ++g) {
            const __bf16* ga = A + (size_t)(m0 + g * 32 + srow) * lda + k0 + scol;
            gload16(ga, &As[(g * 32 + wid * 8) * 64]);
        }
        #pragma unroll
        for (int g = 0; g < BN / 32; ++g) {
            const __bf16* gb = Bt + (size_t)(n0 + g * 32 + srow) * ldb + k0 + scol;
            gload16(gb, &Bs[(g * 32 + wid * 8) * 64]);
        }
        __syncthreads();
        #pragma unroll
        for (int kk = 0; kk < 64; kk += 32) {
            bf16x8 fa[FM], fb[4];
            #pragma unroll
            for (int m = 0; m < FM; ++m)
                fa[m] = *reinterpret_cast<const bf16x8*>(
                    &As[(wr * (16 * FM) + m * 16 + lr) * 64 + kk + kg]);
            #pragma unroll
            for (int n = 0; n < 4; ++n)
                fb[n] = *reinterpret_cast<const bf16x8*>(
                    &Bs[(wc * 64 + n * 16 + lr) * 64 + kk + kg]);
            #pragma unroll
            for (int m = 0; m < FM; ++m)
                #pragma unroll
                for (int n = 0; n < 4; ++n)
                    acc[m][n] = __builtin_amdgcn_mfma_f32_16x16x32_bf16(
                        fa[m], fb[n], acc[m][n], 0, 0, 0);
        }
        __syncthreads();
    }

    const int cr = (lane >> 4) * 4;
    const int cc = lane & 15;
    #pragma unroll
    for (int n = 0; n < 4; ++n) {
        const int gcol = n0 + wc * 64 + n * 16 + cc;
        const float bb = bias[gcol];
        #pragma unroll
        for (int m = 0; m < FM; ++m) {
            #pragma unroll
            for (int j = 0; j < 4; ++j) {
                const int grow = m0 + wr * (16 * FM) + m * 16 + cr + j;
                float v = acc[m][n][j] + bb;
                if (outMode == 1 || outMode == 2) v = fmaxf(v, 0.0f);
                if (outMode >= 2) Cb[(size_t)grow * ldc + gcol] = (__bf16)v;
                else              Cf[(size_t)grow * ldc + gcol] = v;
            }
        }
    }
}

// ---------------------------------------------------------------------------
// fp32 GEMM (input proj, w_map, GAT g1/g2)
// ---------------------------------------------------------------------------
__global__ __launch_bounds__(256) void gemm_bias(
    const float* __restrict__ A, int lda,
    const float* __restrict__ B, int ldb,
    const float* __restrict__ bias,
    float* __restrict__ C, int ldc,
    int M, int N, int K, int relu)
{
    __shared__ float As[16][68];
    __shared__ float Bs[16][68];
    const int tid = threadIdx.x;
    const int tx = tid & 15, ty = tid >> 4;
    const int m0 = blockIdx.y * 64, n0 = blockIdx.x * 64;
    const int liA_m = tid >> 2;
    const int liA_k = (tid & 3) * 4;
    const int liB_n = (tid & 15) * 4;
    const int liB_k = tid >> 4;
    float acc[4][4] = {};
    for (int k0 = 0; k0 < K; k0 += 16) {
        float4 av = *reinterpret_cast<const float4*>(&A[(size_t)(m0 + liA_m) * lda + k0 + liA_k]);
        float4 bv = *reinterpret_cast<const float4*>(&B[(size_t)(k0 + liB_k) * ldb + n0 + liB_n]);
        As[liA_k + 0][liA_m] = av.x;
        As[liA_k + 1][liA_m] = av.y;
        As[liA_k + 2][liA_m] = av.z;
        As[liA_k + 3][liA_m] = av.w;
        *reinterpret_cast<float4*>(&Bs[liB_k][liB_n]) = bv;
        __syncthreads();
        #pragma unroll
        for (int kk = 0; kk < 16; ++kk) {
            float4 a4 = *reinterpret_cast<const float4*>(&As[kk][ty * 4]);
            float4 b4 = *reinterpret_cast<const float4*>(&Bs[kk][tx * 4]);
            float a[4] = {a4.x, a4.y, a4.z, a4.w};
            float b[4] = {b4.x, b4.y, b4.z, b4.w};
            #pragma unroll
            for (int i = 0; i < 4; ++i)
                #pragma unroll
                for (int j = 0; j < 4; ++j)
                    acc[i][j] += a[i] * b[j];
        }
        __syncthreads();
    }
    #pragma unroll
    for (int i = 0; i < 4; ++i) {
        const int m = m0 + ty * 4 + i;
        #pragma unroll
        for (int j = 0; j < 4; ++j) {
            const int n = n0 + tx * 4 + j;
            float v = acc[i][j] + bias[n];
            if (relu) v = fmaxf(v, 0.0f);
            C[(size_t)m * ldc + n] = v;
        }
    }
}

// ---------------------------------------------------------------------------
// Tiled transpose + fp32->bf16: in [L][K][N] -> out [L][N][K]
// ---------------------------------------------------------------------------
__global__ __launch_bounds__(256) void transpose_w(
    const float* __restrict__ in, __bf16* __restrict__ out, int K, int N)
{
    __shared__ __bf16 t[32][33];
    const int l = blockIdx.z;
    in  += (size_t)l * K * N;
    out += (size_t)l * K * N;
    const int k0 = blockIdx.y * 32, n0 = blockIdx.x * 32;
    const int tx = threadIdx.x & 31, ty = threadIdx.x >> 5;
    #pragma unroll
    for (int i = 0; i < 32; i += 8)
        t[ty + i][tx] = (__bf16)in[(size_t)(k0 + ty + i) * N + n0 + tx];
    __syncthreads();
    #pragma unroll
    for (int i = 0; i < 32; i += 8)
        out[(size_t)(n0 + ty + i) * K + k0 + tx] = t[tx][ty + i];
}

// ---------------------------------------------------------------------------
__global__ __launch_bounds__(256) void conv_bf16(
    const float* __restrict__ in, __bf16* __restrict__ out, int total4)
{
    const int i = blockIdx.x * 256 + threadIdx.x;
    if (i >= total4) return;
    const float4 v = *reinterpret_cast<const float4*>(&in[(size_t)i * 4]);
    bf16x4 w;
    w[0] = (__bf16)v.x; w[1] = (__bf16)v.y; w[2] = (__bf16)v.z; w[3] = (__bf16)v.w;
    *reinterpret_cast<bf16x4*>(&out[(size_t)i * 4]) = w;
}

// ---------------------------------------------------------------------------
__global__ __launch_bounds__(256) void permute_in(
    const float* __restrict__ in, float* __restrict__ out, int L, int CH, int total)
{
    const int idx = blockIdx.x * 256 + threadIdx.x;
    if (idx >= total) return;
    const int c = idx % CH;
    const int r = idx / CH;       // r = l*512 + n
    const int n = r & 511;
    const int l = r >> 9;
    out[((size_t)n * L + l) * CH + c] = in[idx];
}

// ---------------------------------------------------------------------------
// Permute F (16384 x 64): node-major row n*32+t -> t-major row t*512+n
// ---------------------------------------------------------------------------
__global__ __launch_bounds__(256) void permute_F(
    const float* __restrict__ in, float* __restrict__ out)
{
    const int idx = blockIdx.x * 256 + threadIdx.x;   // 16384*64 total
    const int c = idx & 63;
    const int r = idx >> 6;
    const int n = r >> 5;
    const int t = r & 31;
    out[((size_t)(t * 512 + n)) * 64 + c] = in[idx];
}

// ---------------------------------------------------------------------------
// MFMA attention: one wave per (node, head). bf16 in/out, fp32 softmax.
// Q[LQ][64], K[LK][64] (token-major = Bt layout), V transposed in LDS.
// Fragment layouts identical to the (validated) gemm_bf16.
// ---------------------------------------------------------------------------
template<int LQ, int LK, bool CAUSAL>
__global__ __launch_bounds__(64) void attn_mfma(
    const __bf16* __restrict__ Q, int ldq,
    const __bf16* __restrict__ Kp, int ldk,
    const __bf16* __restrict__ Vp, int ldv,
    __bf16* __restrict__ O, int ldo)
{
    constexpr int QF = LQ / 16, KF = LK / 16;
    constexpr int KSTR = 72;          // k stride for Qs/Ks (16B-aligned, conflict-spread)
    constexpr int PSTR = LK + 8;      // col stride for Ps / kv stride for Vt
    __shared__ __bf16 Qs[LQ * KSTR];
    __shared__ __bf16 Ks[LK * KSTR];
    __shared__ __bf16 Vt[64 * PSTR];
    __shared__ __bf16 Ps[LQ * PSTR];
    const int n = blockIdx.x >> 3;
    const int h = blockIdx.x & 7;
    const int lane = threadIdx.x;
    const int lr = lane & 15;
    const int g4 = lane >> 4;
    const int kg = g4 * 8;

    if (lane < LQ) {
        #pragma unroll
        for (int j = 0; j < 8; ++j)
            *reinterpret_cast<bf16x8*>(&Qs[lane * KSTR + j * 8]) =
                *reinterpret_cast<const bf16x8*>(&Q[(size_t)(n * LQ + lane) * ldq + h * 64 + j * 8]);
    }
    if (lane < LK) {
        #pragma unroll
        for (int j = 0; j < 8; ++j)
            *reinterpret_cast<bf16x8*>(&Ks[lane * KSTR + j * 8]) =
                *reinterpret_cast<const bf16x8*>(&Kp[(size_t)(n * LK + lane) * ldk + h * 64 + j * 8]);
        #pragma unroll
        for (int j = 0; j < 8; ++j) {
            bf16x8 vv = *reinterpret_cast<const bf16x8*>(&Vp[(size_t)(n * LK + lane) * ldv + h * 64 + j * 8]);
            #pragma unroll
            for (int e = 0; e < 8; ++e)
                Vt[(j * 8 + e) * PSTR + lane] = vv[e];
        }
    }
    __syncthreads();

    // ---- S = (Q K^T) * 0.125 ----
    f32x4 s[QF][KF];
    #pragma unroll
    for (int qi = 0; qi < QF; ++qi)
        #pragma unroll
        for (int ki = 0; ki < KF; ++ki)
            s[qi][ki] = (f32x4){0.0f, 0.0f, 0.0f, 0.0f};
    #pragma unroll
    for (int kk = 0; kk < 64; kk += 32) {
        bf16x8 fa[QF], fb[KF];
        #pragma unroll
        for (int qi = 0; qi < QF; ++qi)
            fa[qi] = *reinterpret_cast<const bf16x8*>(&Qs[(qi * 16 + lr) * KSTR + kk + kg]);
        #pragma unroll
        for (int ki = 0; ki < KF; ++ki)
            fb[ki] = *reinterpret_cast<const bf16x8*>(&Ks[(ki * 16 + lr) * KSTR + kk + kg]);
        #pragma unroll
        for (int qi = 0; qi < QF; ++qi)
            #pragma unroll
            for (int ki = 0; ki < KF; ++ki)
                s[qi][ki] = __builtin_amdgcn_mfma_f32_16x16x32_bf16(fa[qi], fb[ki], s[qi][ki], 0, 0, 0);
    }

    // ---- softmax per row r = qi*16 + g4*4 + j (16-lane-group shuffle) ----
    float inv_s[QF][4];
    #pragma unroll
    for (int qi = 0; qi < QF; ++qi) {
        #pragma unroll
        for (int j = 0; j < 4; ++j) {
            const int row = qi * 16 + g4 * 4 + j;
            float mx = -1e30f;
            #pragma unroll
            for (int ki = 0; ki < KF; ++ki) {
                float v = s[qi][ki][j] * 0.125f;
                if (CAUSAL) { const int col = ki * 16 + lr; if (col > row) v = -1e30f; }
                s[qi][ki][j] = v;
                mx = fmaxf(mx, v);
            }
            #pragma unroll
            for (int d = 1; d < 16; d <<= 1) mx = fmaxf(mx, __shfl_xor(mx, d));
            float sum = 0.0f;
            #pragma unroll
            for (int ki = 0; ki < KF; ++ki) {
                const float p = __expf(s[qi][ki][j] - mx);
                s[qi][ki][j] = p;
                sum += p;
            }
            #pragma unroll
            for (int d = 1; d < 16; d <<= 1) sum += __shfl_xor(sum, d);
            inv_s[qi][j] = 1.0f / sum;
            #pragma unroll
            for (int ki = 0; ki < KF; ++ki)
                Ps[row * PSTR + ki * 16 + lr] = (__bf16)s[qi][ki][j];
        }
    }
    __syncthreads();

    // ---- O = P V (then normalize by row sum) ----
    f32x4 o[QF][4];
    #pragma unroll
    for (int qi = 0; qi < QF; ++qi)
        #pragma unroll
        for (int di = 0; di < 4; ++di)
            o[qi][di] = (f32x4){0.0f, 0.0f, 0.0f, 0.0f};
    #pragma unroll
    for (int kk = 0; kk < LK; kk += 32) {
        bf16x8 fa[QF], fb[4];
        #pragma unroll
        for (int qi = 0; qi < QF; ++qi)
            fa[qi] = *reinterpret_cast<const bf16x8*>(&Ps[(qi * 16 + lr) * PSTR + kk + kg]);
        #pragma unroll
        for (int di = 0; di < 4; ++di)
            fb[di] = *reinterpret_cast<const bf16x8*>(&Vt[(di * 16 + lr) * PSTR + kk + kg]);
        #pragma unroll
        for (int qi = 0; qi < QF; ++qi)
            #pragma unroll
            for (int di = 0; di < 4; ++di)
                o[qi][di] = __builtin_amdgcn_mfma_f32_16x16x32_bf16(fa[qi], fb[di], o[qi][di], 0, 0, 0);
    }
    #pragma unroll
    for (int qi = 0; qi < QF; ++qi)
        #pragma unroll
        for (int di = 0; di < 4; ++di)
            #pragma unroll
            for (int j = 0; j < 4; ++j) {
                const int row = qi * 16 + g4 * 4 + j;
                O[(size_t)(n * LQ + row) * ldo + h * 64 + di * 16 + lr] =
                    (__bf16)(o[qi][di][j] * inv_s[qi][j]);
            }
}

// ---------------------------------------------------------------------------
// LayerNorm(512) bf16: out = LN(x [+ d]) * g + b, fp32 math.
// ---------------------------------------------------------------------------
template<bool HASR, bool F32OUT>
__global__ __launch_bounds__(256) void ln_bf16(
    const __bf16* __restrict__ X, const __bf16* __restrict__ Rb,
    const float* __restrict__ g, const float* __restrict__ b,
    __bf16* __restrict__ outb, float* __restrict__ outf, int ntok)
{
    const int wid = threadIdx.x >> 6, lane = threadIdx.x & 63;
    const int row = blockIdx.x * 4 + wid;
    if (row >= ntok) return;
    const size_t base = (size_t)row * 512;
    float v[8];
    float s = 0.0f;
    #pragma unroll
    for (int j = 0; j < 8; ++j) {
        float t = (float)X[base + j * 64 + lane];
        if (HASR) t += (float)Rb[base + j * 64 + lane];
        v[j] = t; s += t;
    }
    #pragma unroll
    for (int d = 32; d >= 1; d >>= 1) s += __shfl_xor(s, d, 64);
    const float mean = s * (1.0f / 512.0f);
    float vs = 0.0f;
    #pragma unroll
    for (int j = 0; j < 8; ++j) { const float d = v[j] - mean; vs += d * d; }
    #pragma unroll
    for (int d = 32; d >= 1; d >>= 1) vs += __shfl_xor(vs, d, 64);
    const float rstd = rsqrtf(vs * (1.0f / 512.0f) + 1e-5f);
    #pragma unroll
    for (int j = 0; j < 8; ++j) {
        const int c = j * 64 + lane;
        const float val = (v[j] - mean) * rstd * g[c] + b[c];
        if (F32OUT) outf[base + c] = val;
        else        outb[base + c] = (__bf16)val;
    }
}

// ---------------------------------------------------------------------------
__global__ __launch_bounds__(256) void add_posenc(float* __restrict__ x, int L, int total)
{
    const int idx = blockIdx.x * 256 + threadIdx.x;
    if (idx >= total) return;
    const int d = idx & 511;
    const int row = idx >> 9;
    const int l = row % L;
    const int i2 = d & ~1;
    const float freq = expf(-9.210340371976184f * (float)i2 / 512.0f);
    const float a = (float)l * freq;
    x[idx] += (d & 1) ? cosf(a) : sinf(a);
}

// ---------------------------------------------------------------------------
__global__ void zero_ints(int* __restrict__ p, int n)
{
    const int i = blockIdx.x * 256 + threadIdx.x;
    if (i < n) p[i] = 0;
}

__global__ void count_deg(const int* __restrict__ edst, int* __restrict__ deg)
{
    const int e = blockIdx.x * 256 + threadIdx.x;
    if (e < NEDGE) atomicAdd(&deg[edst[e]], 1);
}

__global__ void scan512(const int* __restrict__ deg, int* __restrict__ off)
{
    __shared__ int s[512];
    const int tid = threadIdx.x;
    s[tid] = deg[tid];
    __syncthreads();
    for (int d = 1; d < 512; d <<= 1) {
        const int t = (tid >= d) ? s[tid - d] : 0;
        __syncthreads();
        s[tid] += t;
        __syncthreads();
    }
    off[tid + 1] = s[tid];
    if (tid == 0) off[0] = 0;
}

__global__ void fill_eid(const int* __restrict__ edst, const int* __restrict__ off,
                         int* __restrict__ cur, int* __restrict__ eid)
{
    const int e = blockIdx.x * 256 + threadIdx.x;
    if (e < NEDGE) {
        const int d = edst[e];
        const int pos = off[d] + atomicAdd(&cur[d], 1);
        eid[pos] = e;
    }
}

// ---------------------------------------------------------------------------
// GATv2 (online softmax, t-major tensors: row = t*512 + node).
// For a fixed t all gathered rows live in one contiguous 512KB slab -> L2.
// ---------------------------------------------------------------------------
template<bool FINAL>
__global__ __launch_bounds__(256) void gatv2_kernel(
    const float* __restrict__ xl, const float* __restrict__ xr,
    const float* __restrict__ att, const float* __restrict__ bias,
    const int* __restrict__ off, const int* __restrict__ eid,
    const int* __restrict__ esrc,
    float* __restrict__ outf, float* __restrict__ outd)
{
    const int blk = blockIdx.x;       // t*NNODE + i  (== t-major row)
    const int i = blk & (NNODE - 1);
    const int t = blk >> 9;
    const int tid = threadIdx.x;
    const float xrv = xr[(size_t)blk * 256 + tid];
    const float av = att[tid];
    const int e0 = off[i], e1 = off[i + 1];
    float m = -1e30f, den = 0.0f, acc = 0.0f;
    for (int idx = e0; idx < e1; ++idx) {
        const int e = eid[idx];
        const int s = esrc[e];
        const float xlv = xl[((size_t)(t * 512 + s)) * 256 + tid];
        float z = xlv + xrv;
        z = (z > 0.0f) ? z : 0.2f * z;
        float w = z * av;
        #pragma unroll
        for (int d = 16; d >= 1; d >>= 1) w += __shfl_xor(w, d, 32);
        const float mn = fmaxf(m, w);
        const float sc = expf(m - mn);
        const float p  = expf(w - mn);
        den = den * sc + p;
        acc = acc * sc + p * xlv;
        m = mn;
    }
    float o = (den > 0.0f) ? acc / den : 0.0f;
    o += bias[tid];
    if (FINAL) {
        o = fmaxf(o, 0.0f);
        outd[(size_t)blk * 256 + tid] = o;
    } else {
        outf[(size_t)blk * 256 + tid] = o;   // t-major
    }
}

// ---------------------------------------------------------------------------
extern "C" void kernel_launch(void* const* d_in, const int* in_sizes, int n_in,
                              void* d_out, int out_size, void* d_ws, size_t ws_size,
                              hipStream_t stream)
{
    const float* src       = (const float*)d_in[0];
    const float* tgt       = (const float*)d_in[1];
    const float* w_enc_in  = (const float*)d_in[2];
    const float* b_enc_in  = (const float*)d_in[3];
    const float* w_dec_in  = (const float*)d_in[4];
    const float* b_dec_in  = (const float*)d_in[5];
    const float* w_map     = (const float*)d_in[6];
    const float* b_map     = (const float*)d_in[7];
    const float* enc_qkv_w = (const float*)d_in[8];
    const float* enc_qkv_b = (const float*)d_in[9];
    const float* enc_out_w = (const float*)d_in[10];
    const float* enc_out_b = (const float*)d_in[11];
    const float* enc_ff1_w = (const float*)d_in[12];
    const float* enc_ff1_b = (const float*)d_in[13];
    const float* enc_ff2_w = (const float*)d_in[14];
    const float* enc_ff2_b = (const float*)d_in[15];
    const float* enc_ln1_g = (const float*)d_in[16];
    const float* enc_ln1_b = (const float*)d_in[17];
    const float* enc_ln2_g = (const float*)d_in[18];
    const float* enc_ln2_b = (const float*)d_in[19];
    const float* enc_fn_g  = (const float*)d_in[20];
    const float* enc_fn_b  = (const float*)d_in[21];
    const float* dec_sa_qkv_w = (const float*)d_in[22];
    const float* dec_sa_qkv_b = (const float*)d_in[23];
    const float* dec_sa_out_w = (const float*)d_in[24];
    const float* dec_sa_out_b = (const float*)d_in[25];
    const float* dec_ca_qkv_w = (const float*)d_in[26];
    const float* dec_ca_qkv_b = (const float*)d_in[27];
    const float* dec_ca_out_w = (const float*)d_in[28];
    const float* dec_ca_out_b = (const float*)d_in[29];
    const float* dec_ff1_w = (const float*)d_in[30];
    const float* dec_ff1_b = (const float*)d_in[31];
    const float* dec_ff2_w = (const float*)d_in[32];
    const float* dec_ff2_b = (const float*)d_in[33];
    const float* dec_ln1_g = (const float*)d_in[34];
    const float* dec_ln1_b = (const float*)d_in[35];
    const float* dec_ln2_g = (const float*)d_in[36];
    const float* dec_ln2_b = (const float*)d_in[37];
    const float* dec_ln3_g = (const float*)d_in[38];
    const float* dec_ln3_b = (const float*)d_in[39];
    const float* dec_fn_g  = (const float*)d_in[40];
    const float* dec_fn_b  = (const float*)d_in[41];
    const float* g1_wl   = (const float*)d_in[42];
    const float* g1_wr   = (const float*)d_in[43];
    const float* g1_bl   = (const float*)d_in[44];
    const float* g1_br   = (const float*)d_in[45];
    const float* g1_att  = (const float*)d_in[46];
    const float* g1_bias = (const float*)d_in[47];
    const float* g2_wl   = (const float*)d_in[48];
    const float* g2_wr   = (const float*)d_in[49];
    const float* g2_bl   = (const float*)d_in[50];
    const float* g2_br   = (const float*)d_in[51];
    const float* g2_att  = (const float*)d_in[52];
    const float* g2_bias = (const float*)d_in[53];
    const int*   edge_index = (const int*)d_in[54];
    const int* esrc = edge_index;
    const int* edst = edge_index + NEDGE;

    // ---- lean full-batch layout (floats; total ~149 MiB) ----
    float* wsf = (float*)d_ws;
    __bf16* Xb = (__bf16*)wsf;                          // 32768x512 bf16
    __bf16* Yb = (__bf16*)(wsf + 8388608);              // 16384x512 bf16
    float*  Rf = wsf + 12582912;                        // R region: 8,388,608 f
    float*  Mf = wsf + 20971520;                        // M region: 8,388,608 f
    float*  Wf = wsf + 29360128;                        // W region: 8,388,608 f
    float*  F  = wsf + 37748736;                        // 1,048,576 f
    int* ipool = (int*)(wsf + 38797312);
    int* deg = ipool;
    int* off = deg + 512;
    int* cur = off + 516;
    int* eid = cur + 512;
    __bf16* Rb16 = (__bf16*)Rf;
    __bf16* Mb16 = (__bf16*)Mf;
    __bf16* Wb   = (__bf16*)Wf;

    auto gemm = [&](const float* A, int lda, const float* B, int ldb, const float* bias,
                    float* Cc, int ldc, int M, int N, int K, int relu) {
        dim3 grid((unsigned)(N / 64), (unsigned)(M / 64));
        gemm_bias<<<grid, 256, 0, stream>>>(A, lda, B, ldb, bias, Cc, ldc, M, N, K, relu);
    };
    auto gemmT = [&](const __bf16* A, int lda, const __bf16* Bt, int ldb,
                     const float* bias, float* Cf, __bf16* Cb, int ldc,
                     int M, int N, int K, int mode) {
        dim3 grid((unsigned)(N / 128), (unsigned)(M / 128));
        gemm_bf16<128><<<grid, 256, 0, stream>>>(A, lda, Bt, ldb, bias, Cf, Cb, ldc, M, N, K, mode);
    };
    auto gemmT64 = [&](const __bf16* A, int lda, const __bf16* Bt, int ldb,
                       const float* bias, float* Cf, __bf16* Cb, int ldc,
                       int M, int N, int K, int mode) {
        dim3 grid((unsigned)(N / 64), (unsigned)(M / 128));
        gemm_bf16<64><<<grid, 256, 0, stream>>>(A, lda, Bt, ldb, bias, Cf, Cb, ldc, M, N, K, mode);
    };
    auto tw = [&](const float* w, __bf16* o, int K, int N) {
        dim3 g((unsigned)(N / 32), (unsigned)(K / 32), NLAYER);
        transpose_w<<<g, 256, 0, stream>>>(w, o, K, N);
    };

    // ---- CSR build ----
    zero_ints<<<8, 256, 0, stream>>>(ipool, 512 + 516 + 512);
    count_deg<<<NEDGE / 256, 256, 0, stream>>>(edst, deg);
    scan512<<<1, 512, 0, stream>>>(deg, off);
    fill_eid<<<NEDGE / 256, 256, 0, stream>>>(edst, off, cur, eid);

    // ---- input permute + fp32 projections + posenc + convert to bf16 ----
    {
        float* src_nm = Wf;
        float* Xtmp = Rf;                       // spans R+M
        permute_in<<<4096, 256, 0, stream>>>(src, src_nm, SLEN, 32, 32768 * 32);
        gemm(src_nm, 32, w_enc_in, 512, b_enc_in, Xtmp, 512, 32768, 512, 32, 0);
        add_posenc<<<(32768 * 512) / 256, 256, 0, stream>>>(Xtmp, SLEN, 32768 * 512);
        conv_bf16<<<16384, 256, 0, stream>>>(Xtmp, Xb, 32768 * 128);
        float* tgt_nm = Wf;
        float* Ytmp = Rf;
        permute_in<<<4096, 256, 0, stream>>>(tgt, tgt_nm, TLEN, 64, 16384 * 64);
        gemm(tgt_nm, 64, w_dec_in, 512, b_dec_in, Ytmp, 512, 16384, 512, 64, 0);
        add_posenc<<<(16384 * 512) / 256, 256, 0, stream>>>(Ytmp, TLEN, 16384 * 512);
        conv_bf16<<<8192, 256, 0, stream>>>(Ytmp, Yb, 16384 * 128);
    }

    // ---- encoder weights -> W (bf16, transposed) ----
    __bf16* WeQkv = Wb + 0;
    __bf16* WeOut = Wb + 3145728;
    __bf16* WeFf1 = Wb + 4194304;
    __bf16* WeFf2 = Wb + 8388608;
    tw(enc_qkv_w, WeQkv, 512, 1536);
    tw(enc_out_w, WeOut, 512, 512);
    tw(enc_ff1_w, WeFf1, 512, 2048);
    tw(enc_ff2_w, WeFf2, 2048, 512);

    // ================= encoder (full batch, 32768 rows) =================
    for (int i = 0; i < NLAYER; ++i) {
        for (int c = 0; c < 4; ++c) {
            gemmT(Xb + (size_t)c * 8192 * 512, 512, WeQkv + (size_t)i * 786432, 512,
                  enc_qkv_b + (size_t)i * 1536, nullptr, Rb16, 1536, 8192, 1536, 512, 3);
            attn_mfma<64, 64, false><<<1024, 64, 0, stream>>>(
                Rb16, 1536, Rb16 + 512, 1536, Rb16 + 1024, 1536,
                Mb16 + (size_t)c * 8192 * 512, 512);
        }
        gemmT(Mb16, 512, WeOut + (size_t)i * 262144, 512, enc_out_b + (size_t)i * 512,
              nullptr, Rb16, 512, 32768, 512, 512, 3);
        ln_bf16<true, false><<<8192, 256, 0, stream>>>(Xb, Rb16,
            enc_ln1_g + (size_t)i * 512, enc_ln1_b + (size_t)i * 512, Xb, nullptr, 32768);
        for (int s = 0; s < 4; ++s) {
            gemmT(Xb + (size_t)s * 8192 * 512, 512, WeFf1 + (size_t)i * 1048576, 512,
                  enc_ff1_b + (size_t)i * 2048, nullptr, Mb16, 2048, 8192, 2048, 512, 2);
            gemmT64(Mb16, 2048, WeFf2 + (size_t)i * 1048576, 2048,
                    enc_ff2_b + (size_t)i * 512, nullptr, Rb16 + (size_t)s * 8192 * 512, 512,
                    8192, 512, 2048, 3);
        }
        ln_bf16<true, false><<<8192, 256, 0, stream>>>(Xb, Rb16,
            enc_ln2_g + (size_t)i * 512, enc_ln2_b + (size_t)i * 512, Xb, nullptr, 32768);
    }
    ln_bf16<false, false><<<8192, 256, 0, stream>>>(Xb, nullptr, enc_fn_g, enc_fn_b,
                                                    Xb, nullptr, 32768);
    // Xb is now MEMb

    // ---- decoder weights -> W ----
    __bf16* WdSaQkv = Wb + 0;
    __bf16* WdSaOut = Wb + 3145728;
    __bf16* WdCaQkv = Wb + 4194304;
    __bf16* WdCaOut = Wb + 7340032;
    __bf16* WdFf1   = Wb + 8388608;
    __bf16* WdFf2   = Wb + 12582912;
    tw(dec_sa_qkv_w, WdSaQkv, 512, 1536);
    tw(dec_sa_out_w, WdSaOut, 512, 512);
    tw(dec_ca_qkv_w, WdCaQkv, 512, 1536);
    tw(dec_ca_out_w, WdCaOut, 512, 512);
    tw(dec_ff1_w,    WdFf1,   512, 2048);
    tw(dec_ff2_w,    WdFf2,   2048, 512);

    // ================= decoder (full batch, 16384 rows) =================
    __bf16* ObD  = Mb16;
    __bf16* QbC  = Mb16;
    __bf16* ObCA = (__bf16*)(Mf + 2097152);
    for (int i = 0; i < NLAYER; ++i) {
        for (int c = 0; c < 2; ++c) {
            gemmT(Yb + (size_t)c * 8192 * 512, 512, WdSaQkv + (size_t)i * 786432, 512,
                  dec_sa_qkv_b + (size_t)i * 1536, nullptr, Rb16, 1536, 8192, 1536, 512, 3);
            attn_mfma<32, 32, true><<<2048, 64, 0, stream>>>(
                Rb16, 1536, Rb16 + 512, 1536, Rb16 + 1024, 1536,
                ObD + (size_t)c * 8192 * 512, 512);
        }
        gemmT64(ObD, 512, WdSaOut + (size_t)i * 262144, 512, dec_sa_out_b + (size_t)i * 512,
                nullptr, Rb16, 512, 16384, 512, 512, 3);
        ln_bf16<true, false><<<4096, 256, 0, stream>>>(Yb, Rb16,
            dec_ln1_g + (size_t)i * 512, dec_ln1_b + (size_t)i * 512, Yb, nullptr, 16384);
        for (int c = 0; c < 2; ++c) {
            gemmT64(Yb + (size_t)c * 8192 * 512, 512, WdCaQkv + (size_t)i * 786432, 512,
                    dec_ca_qkv_b + (size_t)i * 1536, nullptr, QbC, 512, 8192, 512, 512, 3);
            gemmT(Xb + (size_t)c * 16384 * 512, 512, WdCaQkv + (size_t)i * 786432 + 262144, 512,
                  dec_ca_qkv_b + (size_t)i * 1536 + 512, nullptr, Rb16, 1024, 16384, 1024, 512, 3);
            attn_mfma<32, 64, false><<<2048, 64, 0, stream>>>(
                QbC, 512, Rb16, 1024, Rb16 + 512, 1024,
                ObCA + (size_t)c * 8192 * 512, 512);
        }
        gemmT64(ObCA, 512, WdCaOut + (size_t)i * 262144, 512, dec_ca_out_b + (size_t)i * 512,
                nullptr, Rb16, 512, 16384, 512, 512, 3);
        ln_bf16<true, false><<<4096, 256, 0, stream>>>(Yb, Rb16,
            dec_ln2_g + (size_t)i * 512, dec_ln2_b + (size_t)i * 512, Yb, nullptr, 16384);
        for (int s = 0; s < 2; ++s) {
            gemmT(Yb + (size_t)s * 8192 * 512, 512, WdFf1 + (size_t)i * 1048576, 512,
                  dec_ff1_b + (size_t)i * 2048, nullptr, Mb16, 2048, 8192, 2048, 512, 2);
            gemmT64(Mb16, 2048, WdFf2 + (size_t)i * 1048576, 2048,
                    dec_ff2_b + (size_t)i * 512, nullptr, Rb16 + (size_t)s * 8192 * 512, 512,
                    8192, 512, 2048, 3);
        }
        ln_bf16<true, false><<<4096, 256, 0, stream>>>(Yb, Rb16,
            dec_ln3_g + (size_t)i * 512, dec_ln3_b + (size_t)i * 512, Yb, nullptr, 16384);
    }
    // final decoder LN -> fp32 in R
    float* Yf = Rf;
    ln_bf16<false, true><<<4096, 256, 0, stream>>>(Yb, nullptr, dec_fn_g, dec_fn_b,
                                                   nullptr, Yf, 16384);

    // map to FEAT=64 (node-major), then permute to t-major
    gemm(Yf, 512, w_map, 64, b_map, F, 64, 16384, 64, 512, 0);
    float* Ft = Wf;                          // 1,048,576 f (W dead)
    permute_F<<<4096, 256, 0, stream>>>(F, Ft);

    // ================= spatial GATv2 (fp32, t-major) =================
    float* G  = Mf;                          // 4,194,304 f
    float* Hb = Mf + 4194304;                // 4,194,304 f
    float* Ib = Wf + 1048576;                // 4,194,304 f
    gemm(Ft, 64, g1_wl, 256, g1_bl, G,  256, 16384, 256, 64, 0);
    gemm(Ft, 64, g1_wr, 256, g1_br, Hb, 256, 16384, 256, 64, 0);
    gatv2_kernel<false><<<16384, 256, 0, stream>>>(G, Hb, g1_att, g1_bias, off, eid, esrc, Ib, nullptr);
    gemm(Ib, 256, g2_wl, 256, g2_bl, G,  256, 16384, 256, 256, 0);
    gemm(Ib, 256, g2_wr, 256, g2_br, Hb, 256, 16384, 256, 256, 0);
    gatv2_kernel<true><<<16384, 256, 0, stream>>>(G, Hb, g2_att, g2_bias, off, eid, esrc,
                                                  nullptr, (float*)d_out);
}

// Round 11
// 4697.853 us; speedup vs baseline: 1.6014x; 1.0096x over previous
//
#include <hip/hip_runtime.h>
#include <hip/hip_bf16.h>

// Problem constants
#define NHEAD 8
#define SLEN 64
#define TLEN 32
#define NNODE 512
#define NEDGE 16384
#define NLAYER 4

typedef __attribute__((ext_vector_type(8))) __bf16 bf16x8;
typedef __attribute__((ext_vector_type(4))) __bf16 bf16x4;
typedef __attribute__((ext_vector_type(4))) float  f32x4;

// ---------------------------------------------------------------------------
// async global->LDS 16B (wave-uniform LDS base + lane*16 semantics)
// ---------------------------------------------------------------------------
__device__ __forceinline__ void gload16(const void* g, void* l)
{
    __builtin_amdgcn_global_load_lds(
        (const __attribute__((address_space(1))) void*)g,
        (__attribute__((address_space(3))) void*)l, 16, 0, 0);
}

// ---------------------------------------------------------------------------
// bf16 GEMM (m97 structure): A[M][K] bf16, Bt[N][K] bf16 (pre-transposed),
// C = A@B + bias.  outMode: 0=f32, 1=f32+relu, 2=bf16+relu, 3=bf16.
// BM=128, BN template {128,64}.
// ---------------------------------------------------------------------------
template<int BN>
__global__ __launch_bounds__(256) void gemm_bf16(
    const __bf16* __restrict__ A, int lda,
    const __bf16* __restrict__ Bt, int ldb,
    const float* __restrict__ bias,
    float* __restrict__ Cf, __bf16* __restrict__ Cb, int ldc,
    int M, int N, int K, int outMode)
{
    constexpr int FM = (BN == 128) ? 4 : 2;
    __shared__ __bf16 As[128 * 64];
    __shared__ __bf16 Bs[BN * 64];
    const int tid  = threadIdx.x;
    const int wid  = tid >> 6;
    const int lane = tid & 63;
    const int wr = (BN == 128) ? (wid >> 1) : wid;
    const int wc = (BN == 128) ? (wid & 1) : 0;
    const int m0 = blockIdx.y * 128, n0 = blockIdx.x * BN;

    const int srow = wid * 8 + (lane >> 3);
    const int scol = (lane & 7) * 8;
    const int lr = lane & 15;
    const int kg = (lane >> 4) * 8;

    f32x4 acc[FM][4];
    #pragma unroll
    for (int m = 0; m < FM; ++m)
        #pragma unroll
        for (int n = 0; n < 4; ++n)
            acc[m][n] = (f32x4){0.0f, 0.0f, 0.0f, 0.0f};

    for (int k0 = 0; k0 < K; k0 += 64) {
        #pragma unroll
        for (int g = 0; g < 4; ++g) {
            const __bf16* ga = A + (size_t)(m0 + g * 32 + srow) * lda + k0 + scol;
            gload16(ga, &As[(g * 32 + wid * 8) * 64]);
        }
        #pragma unroll
        for (int g = 0; g < BN / 32; ++g) {
            const __bf16* gb = Bt + (size_t)(n0 + g * 32 + srow) * ldb + k0 + scol;
            gload16(gb, &Bs[(g * 32 + wid * 8) * 64]);
        }
        __syncthreads();
        #pragma unroll
        for (int kk = 0; kk < 64; kk += 32) {
            bf16x8 fa[FM], fb[4];
            #pragma unroll
            for (int m = 0; m < FM; ++m)
                fa[m] = *reinterpret_cast<const bf16x8*>(
                    &As[(wr * (16 * FM) + m * 16 + lr) * 64 + kk + kg]);
            #pragma unroll
            for (int n = 0; n < 4; ++n)
                fb[n] = *reinterpret_cast<const bf16x8*>(
                    &Bs[(wc * 64 + n * 16 + lr) * 64 + kk + kg]);
            #pragma unroll
            for (int m = 0; m < FM; ++m)
                #pragma unroll
                for (int n = 0; n < 4; ++n)
                    acc[m][n] = __builtin_amdgcn_mfma_f32_16x16x32_bf16(
                        fa[m], fb[n], acc[m][n], 0, 0, 0);
        }
        __syncthreads();
    }

    const int cr = (lane >> 4) * 4;
    const int cc = lane & 15;
    #pragma unroll
    for (int n = 0; n < 4; ++n) {
        const int gcol = n0 + wc * 64 + n * 16 + cc;
        const float bb = bias[gcol];
        #pragma unroll
        for (int m = 0; m < FM; ++m) {
            #pragma unroll
            for (int j = 0; j < 4; ++j) {
                const int grow = m0 + wr * (16 * FM) + m * 16 + cr + j;
                float v = acc[m][n][j] + bb;
                if (outMode == 1 || outMode == 2) v = fmaxf(v, 0.0f);
                if (outMode >= 2) Cb[(size_t)grow * ldc + gcol] = (__bf16)v;
                else              Cf[(size_t)grow * ldc + gcol] = v;
            }
        }
    }
}

// ---------------------------------------------------------------------------
// fp32 GEMM (input proj, w_map, GAT g1/g2)
// ---------------------------------------------------------------------------
__global__ __launch_bounds__(256) void gemm_bias(
    const float* __restrict__ A, int lda,
    const float* __restrict__ B, int ldb,
    const float* __restrict__ bias,
    float* __restrict__ C, int ldc,
    int M, int N, int K, int relu)
{
    __shared__ float As[16][68];
    __shared__ float Bs[16][68];
    const int tid = threadIdx.x;
    const int tx = tid & 15, ty = tid >> 4;
    const int m0 = blockIdx.y * 64, n0 = blockIdx.x * 64;
    const int liA_m = tid >> 2;
    const int liA_k = (tid & 3) * 4;
    const int liB_n = (tid & 15) * 4;
    const int liB_k = tid >> 4;
    float acc[4][4] = {};
    for (int k0 = 0; k0 < K; k0 += 16) {
        float4 av = *reinterpret_cast<const float4*>(&A[(size_t)(m0 + liA_m) * lda + k0 + liA_k]);
        float4 bv = *reinterpret_cast<const float4*>(&B[(size_t)(k0 + liB_k) * ldb + n0 + liB_n]);
        As[liA_k + 0][liA_m] = av.x;
        As[liA_k + 1][liA_m] = av.y;
        As[liA_k + 2][liA_m] = av.z;
        As[liA_k + 3][liA_m] = av.w;
        *reinterpret_cast<float4*>(&Bs[liB_k][liB_n]) = bv;
        __syncthreads();
        #pragma unroll
        for (int kk = 0; kk < 16; ++kk) {
            float4 a4 = *reinterpret_cast<const float4*>(&As[kk][ty * 4]);
            float4 b4 = *reinterpret_cast<const float4*>(&Bs[kk][tx * 4]);
            float a[4] = {a4.x, a4.y, a4.z, a4.w};
            float b[4] = {b4.x, b4.y, b4.z, b4.w};
            #pragma unroll
            for (int i = 0; i < 4; ++i)
                #pragma unroll
                for (int j = 0; j < 4; ++j)
                    acc[i][j] += a[i] * b[j];
        }
        __syncthreads();
    }
    #pragma unroll
    for (int i = 0; i < 4; ++i) {
        const int m = m0 + ty * 4 + i;
        #pragma unroll
        for (int j = 0; j < 4; ++j) {
            const int n = n0 + tx * 4 + j;
            float v = acc[i][j] + bias[n];
            if (relu) v = fmaxf(v, 0.0f);
            C[(size_t)m * ldc + n] = v;
        }
    }
}

// ---------------------------------------------------------------------------
// Tiled transpose + fp32->bf16: in [L][K][N] -> out [L][N][K]
// ---------------------------------------------------------------------------
__global__ __launch_bounds__(256) void transpose_w(
    const float* __restrict__ in, __bf16* __restrict__ out, int K, int N)
{
    __shared__ __bf16 t[32][33];
    const int l = blockIdx.z;
    in  += (size_t)l * K * N;
    out += (size_t)l * K * N;
    const int k0 = blockIdx.y * 32, n0 = blockIdx.x * 32;
    const int tx = threadIdx.x & 31, ty = threadIdx.x >> 5;
    #pragma unroll
    for (int i = 0; i < 32; i += 8)
        t[ty + i][tx] = (__bf16)in[(size_t)(k0 + ty + i) * N + n0 + tx];
    __syncthreads();
    #pragma unroll
    for (int i = 0; i < 32; i += 8)
        out[(size_t)(n0 + ty + i) * K + k0 + tx] = t[tx][ty + i];
}

// ---------------------------------------------------------------------------
__global__ __launch_bounds__(256) void conv_bf16(
    const float* __restrict__ in, __bf16* __restrict__ out, int total4)
{
    const int i = blockIdx.x * 256 + threadIdx.x;
    if (i >= total4) return;
    const float4 v = *reinterpret_cast<const float4*>(&in[(size_t)i * 4]);
    bf16x4 w;
    w[0] = (__bf16)v.x; w[1] = (__bf16)v.y; w[2] = (__bf16)v.z; w[3] = (__bf16)v.w;
    *reinterpret_cast<bf16x4*>(&out[(size_t)i * 4]) = w;
}

// ---------------------------------------------------------------------------
__global__ __launch_bounds__(256) void permute_in(
    const float* __restrict__ in, float* __restrict__ out, int L, int CH, int total)
{
    const int idx = blockIdx.x * 256 + threadIdx.x;
    if (idx >= total) return;
    const int c = idx % CH;
    const int r = idx / CH;       // r = l*512 + n
    const int n = r & 511;
    const int l = r >> 9;
    out[((size_t)n * L + l) * CH + c] = in[idx];
}

// ---------------------------------------------------------------------------
// Permute F (16384 x 64): node-major row n*32+t -> t-major row t*512+n
// ---------------------------------------------------------------------------
__global__ __launch_bounds__(256) void permute_F(
    const float* __restrict__ in, float* __restrict__ out)
{
    const int idx = blockIdx.x * 256 + threadIdx.x;   // 16384*64 total
    const int c = idx & 63;
    const int r = idx >> 6;
    const int n = r >> 5;
    const int t = r & 31;
    out[((size_t)(t * 512 + n)) * 64 + c] = in[idx];
}

// ---------------------------------------------------------------------------
// MFMA attention v2: one wave per (node, head). Q/K fragments loaded DIRECTLY
// from global (contiguous 16B per fragment); only V-transpose + P in LDS.
// ---------------------------------------------------------------------------
template<int LQ, int LK, bool CAUSAL>
__global__ __launch_bounds__(64) void attn_mfma(
    const __bf16* __restrict__ Q, int ldq,
    const __bf16* __restrict__ Kp, int ldk,
    const __bf16* __restrict__ Vp, int ldv,
    __bf16* __restrict__ O, int ldo)
{
    constexpr int QF = LQ / 16, KF = LK / 16;
    constexpr int PSTR = LK + 8;      // col stride for Ps / kv stride for Vt
    __shared__ __bf16 Vt[64 * PSTR];
    __shared__ __bf16 Ps[LQ * PSTR];
    const int n = blockIdx.x >> 3;
    const int h = blockIdx.x & 7;
    const int lane = threadIdx.x;
    const int lr = lane & 15;
    const int g4 = lane >> 4;
    const int kg = g4 * 8;

    // ---- V transpose into LDS ----
    if (lane < LK) {
        #pragma unroll
        for (int j = 0; j < 8; ++j) {
            bf16x8 vv = *reinterpret_cast<const bf16x8*>(
                &Vp[(size_t)(n * LK + lane) * ldv + h * 64 + j * 8]);
            #pragma unroll
            for (int e = 0; e < 8; ++e)
                Vt[(j * 8 + e) * PSTR + lane] = vv[e];
        }
    }

    // ---- S = (Q K^T) * 0.125 : direct global fragment loads ----
    f32x4 s[QF][KF];
    #pragma unroll
    for (int qi = 0; qi < QF; ++qi)
        #pragma unroll
        for (int ki = 0; ki < KF; ++ki)
            s[qi][ki] = (f32x4){0.0f, 0.0f, 0.0f, 0.0f};
    #pragma unroll
    for (int kk = 0; kk < 64; kk += 32) {
        bf16x8 fa[QF], fb[KF];
        #pragma unroll
        for (int qi = 0; qi < QF; ++qi)
            fa[qi] = *reinterpret_cast<const bf16x8*>(
                &Q[(size_t)(n * LQ + qi * 16 + lr) * ldq + h * 64 + kk + kg]);
        #pragma unroll
        for (int ki = 0; ki < KF; ++ki)
            fb[ki] = *reinterpret_cast<const bf16x8*>(
                &Kp[(size_t)(n * LK + ki * 16 + lr) * ldk + h * 64 + kk + kg]);
        #pragma unroll
        for (int qi = 0; qi < QF; ++qi)
            #pragma unroll
            for (int ki = 0; ki < KF; ++ki)
                s[qi][ki] = __builtin_amdgcn_mfma_f32_16x16x32_bf16(fa[qi], fb[ki], s[qi][ki], 0, 0, 0);
    }

    // ---- softmax per row r = qi*16 + g4*4 + j (16-lane-group shuffle) ----
    float inv_s[QF][4];
    #pragma unroll
    for (int qi = 0; qi < QF; ++qi) {
        #pragma unroll
        for (int j = 0; j < 4; ++j) {
            const int row = qi * 16 + g4 * 4 + j;
            float mx = -1e30f;
            #pragma unroll
            for (int ki = 0; ki < KF; ++ki) {
                float v = s[qi][ki][j] * 0.125f;
                if (CAUSAL) { const int col = ki * 16 + lr; if (col > row) v = -1e30f; }
                s[qi][ki][j] = v;
                mx = fmaxf(mx, v);
            }
            #pragma unroll
            for (int d = 1; d < 16; d <<= 1) mx = fmaxf(mx, __shfl_xor(mx, d));
            float sum = 0.0f;
            #pragma unroll
            for (int ki = 0; ki < KF; ++ki) {
                const float p = __expf(s[qi][ki][j] - mx);
                s[qi][ki][j] = p;
                sum += p;
            }
            #pragma unroll
            for (int d = 1; d < 16; d <<= 1) sum += __shfl_xor(sum, d);
            inv_s[qi][j] = 1.0f / sum;
            #pragma unroll
            for (int ki = 0; ki < KF; ++ki)
                Ps[row * PSTR + ki * 16 + lr] = (__bf16)s[qi][ki][j];
        }
    }
    __syncthreads();

    // ---- O = P V (then normalize by row sum) ----
    f32x4 o[QF][4];
    #pragma unroll
    for (int qi = 0; qi < QF; ++qi)
        #pragma unroll
        for (int di = 0; di < 4; ++di)
            o[qi][di] = (f32x4){0.0f, 0.0f, 0.0f, 0.0f};
    #pragma unroll
    for (int kk = 0; kk < LK; kk += 32) {
        bf16x8 fa[QF], fb[4];
        #pragma unroll
        for (int qi = 0; qi < QF; ++qi)
            fa[qi] = *reinterpret_cast<const bf16x8*>(&Ps[(qi * 16 + lr) * PSTR + kk + kg]);
        #pragma unroll
        for (int di = 0; di < 4; ++di)
            fb[di] = *reinterpret_cast<const bf16x8*>(&Vt[(di * 16 + lr) * PSTR + kk + kg]);
        #pragma unroll
        for (int qi = 0; qi < QF; ++qi)
            #pragma unroll
            for (int di = 0; di < 4; ++di)
                o[qi][di] = __builtin_amdgcn_mfma_f32_16x16x32_bf16(fa[qi], fb[di], o[qi][di], 0, 0, 0);
    }
    #pragma unroll
    for (int qi = 0; qi < QF; ++qi)
        #pragma unroll
        for (int di = 0; di < 4; ++di)
            #pragma unroll
            for (int j = 0; j < 4; ++j) {
                const int row = qi * 16 + g4 * 4 + j;
                O[(size_t)(n * LQ + row) * ldo + h * 64 + di * 16 + lr] =
                    (__bf16)(o[qi][di][j] * inv_s[qi][j]);
            }
}

// ---------------------------------------------------------------------------
// LayerNorm(512) bf16, VECTORIZED: lane owns 8 contiguous channels (bf16x8).
// ---------------------------------------------------------------------------
template<bool HASR, bool F32OUT>
__global__ __launch_bounds__(256) void ln_bf16(
    const __bf16* __restrict__ X, const __bf16* __restrict__ Rb,
    const float* __restrict__ g, const float* __restrict__ b,
    __bf16* __restrict__ outb, float* __restrict__ outf, int ntok)
{
    const int wid = threadIdx.x >> 6, lane = threadIdx.x & 63;
    const int row = blockIdx.x * 4 + wid;
    if (row >= ntok) return;
    const size_t base = (size_t)row * 512;
    const int c0 = lane * 8;
    const bf16x8 xv = *reinterpret_cast<const bf16x8*>(&X[base + c0]);
    float v[8];
    float s = 0.0f;
    if (HASR) {
        const bf16x8 rv = *reinterpret_cast<const bf16x8*>(&Rb[base + c0]);
        #pragma unroll
        for (int j = 0; j < 8; ++j) { v[j] = (float)xv[j] + (float)rv[j]; s += v[j]; }
    } else {
        #pragma unroll
        for (int j = 0; j < 8; ++j) { v[j] = (float)xv[j]; s += v[j]; }
    }
    #pragma unroll
    for (int d = 32; d >= 1; d >>= 1) s += __shfl_xor(s, d, 64);
    const float mean = s * (1.0f / 512.0f);
    float vs = 0.0f;
    #pragma unroll
    for (int j = 0; j < 8; ++j) { const float d = v[j] - mean; vs += d * d; }
    #pragma unroll
    for (int d = 32; d >= 1; d >>= 1) vs += __shfl_xor(vs, d, 64);
    const float rstd = rsqrtf(vs * (1.0f / 512.0f) + 1e-5f);
    const float4 g0 = *reinterpret_cast<const float4*>(&g[c0]);
    const float4 g1 = *reinterpret_cast<const float4*>(&g[c0 + 4]);
    const float4 b0 = *reinterpret_cast<const float4*>(&b[c0]);
    const float4 b1 = *reinterpret_cast<const float4*>(&b[c0 + 4]);
    const float gg[8] = {g0.x, g0.y, g0.z, g0.w, g1.x, g1.y, g1.z, g1.w};
    const float bb[8] = {b0.x, b0.y, b0.z, b0.w, b1.x, b1.y, b1.z, b1.w};
    if (F32OUT) {
        f32x4 o0, o1;
        #pragma unroll
        for (int j = 0; j < 4; ++j) o0[j] = (v[j] - mean) * rstd * gg[j] + bb[j];
        #pragma unroll
        for (int j = 0; j < 4; ++j) o1[j] = (v[4 + j] - mean) * rstd * gg[4 + j] + bb[4 + j];
        *reinterpret_cast<f32x4*>(&outf[base + c0]) = o0;
        *reinterpret_cast<f32x4*>(&outf[base + c0 + 4]) = o1;
    } else {
        bf16x8 w;
        #pragma unroll
        for (int j = 0; j < 8; ++j) w[j] = (__bf16)((v[j] - mean) * rstd * gg[j] + bb[j]);
        *reinterpret_cast<bf16x8*>(&outb[base + c0]) = w;
    }
}

// ---------------------------------------------------------------------------
__global__ __launch_bounds__(256) void add_posenc(float* __restrict__ x, int L, int total)
{
    const int idx = blockIdx.x * 256 + threadIdx.x;
    if (idx >= total) return;
    const int d = idx & 511;
    const int row = idx >> 9;
    const int l = row % L;
    const int i2 = d & ~1;
    const float freq = expf(-9.210340371976184f * (float)i2 / 512.0f);
    const float a = (float)l * freq;
    x[idx] += (d & 1) ? cosf(a) : sinf(a);
}

// ---------------------------------------------------------------------------
__global__ void zero_ints(int* __restrict__ p, int n)
{
    const int i = blockIdx.x * 256 + threadIdx.x;
    if (i < n) p[i] = 0;
}

__global__ void count_deg(const int* __restrict__ edst, int* __restrict__ deg)
{
    const int e = blockIdx.x * 256 + threadIdx.x;
    if (e < NEDGE) atomicAdd(&deg[edst[e]], 1);
}

__global__ void scan512(const int* __restrict__ deg, int* __restrict__ off)
{
    __shared__ int s[512];
    const int tid = threadIdx.x;
    s[tid] = deg[tid];
    __syncthreads();
    for (int d = 1; d < 512; d <<= 1) {
        const int t = (tid >= d) ? s[tid - d] : 0;
        __syncthreads();
        s[tid] += t;
        __syncthreads();
    }
    off[tid + 1] = s[tid];
    if (tid == 0) off[0] = 0;
}

__global__ void fill_eid(const int* __restrict__ edst, const int* __restrict__ off,
                         int* __restrict__ cur, int* __restrict__ eid)
{
    const int e = blockIdx.x * 256 + threadIdx.x;
    if (e < NEDGE) {
        const int d = edst[e];
        const int pos = off[d] + atomicAdd(&cur[d], 1);
        eid[pos] = e;
    }
}

// ---------------------------------------------------------------------------
// GATv2 (online softmax, t-major tensors: row = t*512 + node).
// ---------------------------------------------------------------------------
template<bool FINAL>
__global__ __launch_bounds__(256) void gatv2_kernel(
    const float* __restrict__ xl, const float* __restrict__ xr,
    const float* __restrict__ att, const float* __restrict__ bias,
    const int* __restrict__ off, const int* __restrict__ eid,
    const int* __restrict__ esrc,
    float* __restrict__ outf, float* __restrict__ outd)
{
    const int blk = blockIdx.x;       // t*NNODE + i  (== t-major row)
    const int i = blk & (NNODE - 1);
    const int t = blk >> 9;
    const int tid = threadIdx.x;
    const float xrv = xr[(size_t)blk * 256 + tid];
    const float av = att[tid];
    const int e0 = off[i], e1 = off[i + 1];
    float m = -1e30f, den = 0.0f, acc = 0.0f;
    for (int idx = e0; idx < e1; ++idx) {
        const int e = eid[idx];
        const int s = esrc[e];
        const float xlv = xl[((size_t)(t * 512 + s)) * 256 + tid];
        float z = xlv + xrv;
        z = (z > 0.0f) ? z : 0.2f * z;
        float w = z * av;
        #pragma unroll
        for (int d = 16; d >= 1; d >>= 1) w += __shfl_xor(w, d, 32);
        const float mn = fmaxf(m, w);
        const float sc = __expf(m - mn);
        const float p  = __expf(w - mn);
        den = den * sc + p;
        acc = acc * sc + p * xlv;
        m = mn;
    }
    float o = (den > 0.0f) ? acc / den : 0.0f;
    o += bias[tid];
    if (FINAL) {
        o = fmaxf(o, 0.0f);
        outd[(size_t)blk * 256 + tid] = o;
    } else {
        outf[(size_t)blk * 256 + tid] = o;   // t-major
    }
}

// ---------------------------------------------------------------------------
extern "C" void kernel_launch(void* const* d_in, const int* in_sizes, int n_in,
                              void* d_out, int out_size, void* d_ws, size_t ws_size,
                              hipStream_t stream)
{
    const float* src       = (const float*)d_in[0];
    const float* tgt       = (const float*)d_in[1];
    const float* w_enc_in  = (const float*)d_in[2];
    const float* b_enc_in  = (const float*)d_in[3];
    const float* w_dec_in  = (const float*)d_in[4];
    const float* b_dec_in  = (const float*)d_in[5];
    const float* w_map     = (const float*)d_in[6];
    const float* b_map     = (const float*)d_in[7];
    const float* enc_qkv_w = (const float*)d_in[8];
    const float* enc_qkv_b = (const float*)d_in[9];
    const float* enc_out_w = (const float*)d_in[10];
    const float* enc_out_b = (const float*)d_in[11];
    const float* enc_ff1_w = (const float*)d_in[12];
    const float* enc_ff1_b = (const float*)d_in[13];
    const float* enc_ff2_w = (const float*)d_in[14];
    const float* enc_ff2_b = (const float*)d_in[15];
    const float* enc_ln1_g = (const float*)d_in[16];
    const float* enc_ln1_b = (const float*)d_in[17];
    const float* enc_ln2_g = (const float*)d_in[18];
    const float* enc_ln2_b = (const float*)d_in[19];
    const float* enc_fn_g  = (const float*)d_in[20];
    const float* enc_fn_b  = (const float*)d_in[21];
    const float* dec_sa_qkv_w = (const float*)d_in[22];
    const float* dec_sa_qkv_b = (const float*)d_in[23];
    const float* dec_sa_out_w = (const float*)d_in[24];
    const float* dec_sa_out_b = (const float*)d_in[25];
    const float* dec_ca_qkv_w = (const float*)d_in[26];
    const float* dec_ca_qkv_b = (const float*)d_in[27];
    const float* dec_ca_out_w = (const float*)d_in[28];
    const float* dec_ca_out_b = (const float*)d_in[29];
    const float* dec_ff1_w = (const float*)d_in[30];
    const float* dec_ff1_b = (const float*)d_in[31];
    const float* dec_ff2_w = (const float*)d_in[32];
    const float* dec_ff2_b = (const float*)d_in[33];
    const float* dec_ln1_g = (const float*)d_in[34];
    const float* dec_ln1_b = (const float*)d_in[35];
    const float* dec_ln2_g = (const float*)d_in[36];
    const float* dec_ln2_b = (const float*)d_in[37];
    const float* dec_ln3_g = (const float*)d_in[38];
    const float* dec_ln3_b = (const float*)d_in[39];
    const float* dec_fn_g  = (const float*)d_in[40];
    const float* dec_fn_b  = (const float*)d_in[41];
    const float* g1_wl   = (const float*)d_in[42];
    const float* g1_wr   = (const float*)d_in[43];
    const float* g1_bl   = (const float*)d_in[44];
    const float* g1_br   = (const float*)d_in[45];
    const float* g1_att  = (const float*)d_in[46];
    const float* g1_bias = (const float*)d_in[47];
    const float* g2_wl   = (const float*)d_in[48];
    const float* g2_wr   = (const float*)d_in[49];
    const float* g2_bl   = (const float*)d_in[50];
    const float* g2_br   = (const float*)d_in[51];
    const float* g2_att  = (const float*)d_in[52];
    const float* g2_bias = (const float*)d_in[53];
    const int*   edge_index = (const int*)d_in[54];
    const int* esrc = edge_index;
    const int* edst = edge_index + NEDGE;

    // ---- lean full-batch layout (floats; total ~149 MiB) ----
    float* wsf = (float*)d_ws;
    __bf16* Xb = (__bf16*)wsf;                          // 32768x512 bf16
    __bf16* Yb = (__bf16*)(wsf + 8388608);              // 16384x512 bf16
    float*  Rf = wsf + 12582912;                        // R region: 8,388,608 f
    float*  Mf = wsf + 20971520;                        // M region: 8,388,608 f
    float*  Wf = wsf + 29360128;                        // W region: 8,388,608 f
    float*  F  = wsf + 37748736;                        // 1,048,576 f
    int* ipool = (int*)(wsf + 38797312);
    int* deg = ipool;
    int* off = deg + 512;
    int* cur = off + 516;
    int* eid = cur + 512;
    __bf16* Rb16 = (__bf16*)Rf;
    __bf16* Mb16 = (__bf16*)Mf;
    __bf16* Wb   = (__bf16*)Wf;

    auto gemm = [&](const float* A, int lda, const float* B, int ldb, const float* bias,
                    float* Cc, int ldc, int M, int N, int K, int relu) {
        dim3 grid((unsigned)(N / 64), (unsigned)(M / 64));
        gemm_bias<<<grid, 256, 0, stream>>>(A, lda, B, ldb, bias, Cc, ldc, M, N, K, relu);
    };
    auto gemmT = [&](const __bf16* A, int lda, const __bf16* Bt, int ldb,
                     const float* bias, float* Cf, __bf16* Cb, int ldc,
                     int M, int N, int K, int mode) {
        dim3 grid((unsigned)(N / 128), (unsigned)(M / 128));
        gemm_bf16<128><<<grid, 256, 0, stream>>>(A, lda, Bt, ldb, bias, Cf, Cb, ldc, M, N, K, mode);
    };
    auto gemmT64 = [&](const __bf16* A, int lda, const __bf16* Bt, int ldb,
                       const float* bias, float* Cf, __bf16* Cb, int ldc,
                       int M, int N, int K, int mode) {
        dim3 grid((unsigned)(N / 64), (unsigned)(M / 128));
        gemm_bf16<64><<<grid, 256, 0, stream>>>(A, lda, Bt, ldb, bias, Cf, Cb, ldc, M, N, K, mode);
    };
    auto tw = [&](const float* w, __bf16* o, int K, int N) {
        dim3 g((unsigned)(N / 32), (unsigned)(K / 32), NLAYER);
        transpose_w<<<g, 256, 0, stream>>>(w, o, K, N);
    };

    // ---- CSR build ----
    zero_ints<<<8, 256, 0, stream>>>(ipool, 512 + 516 + 512);
    count_deg<<<NEDGE / 256, 256, 0, stream>>>(edst, deg);
    scan512<<<1, 512, 0, stream>>>(deg, off);
    fill_eid<<<NEDGE / 256, 256, 0, stream>>>(edst, off, cur, eid);

    // ---- input permute + fp32 projections + posenc + convert to bf16 ----
    {
        float* src_nm = Wf;
        float* Xtmp = Rf;                       // spans R+M
        permute_in<<<4096, 256, 0, stream>>>(src, src_nm, SLEN, 32, 32768 * 32);
        gemm(src_nm, 32, w_enc_in, 512, b_enc_in, Xtmp, 512, 32768, 512, 32, 0);
        add_posenc<<<(32768 * 512) / 256, 256, 0, stream>>>(Xtmp, SLEN, 32768 * 512);
        conv_bf16<<<16384, 256, 0, stream>>>(Xtmp, Xb, 32768 * 128);
        float* tgt_nm = Wf;
        float* Ytmp = Rf;
        permute_in<<<4096, 256, 0, stream>>>(tgt, tgt_nm, TLEN, 64, 16384 * 64);
        gemm(tgt_nm, 64, w_dec_in, 512, b_dec_in, Ytmp, 512, 16384, 512, 64, 0);
        add_posenc<<<(16384 * 512) / 256, 256, 0, stream>>>(Ytmp, TLEN, 16384 * 512);
        conv_bf16<<<8192, 256, 0, stream>>>(Ytmp, Yb, 16384 * 128);
    }

    // ---- encoder weights -> W (bf16, transposed) ----
    __bf16* WeQkv = Wb + 0;
    __bf16* WeOut = Wb + 3145728;
    __bf16* WeFf1 = Wb + 4194304;
    __bf16* WeFf2 = Wb + 8388608;
    tw(enc_qkv_w, WeQkv, 512, 1536);
    tw(enc_out_w, WeOut, 512, 512);
    tw(enc_ff1_w, WeFf1, 512, 2048);
    tw(enc_ff2_w, WeFf2, 2048, 512);

    // ================= encoder (full batch, 32768 rows) =================
    for (int i = 0; i < NLAYER; ++i) {
        for (int c = 0; c < 4; ++c) {
            gemmT(Xb + (size_t)c * 8192 * 512, 512, WeQkv + (size_t)i * 786432, 512,
                  enc_qkv_b + (size_t)i * 1536, nullptr, Rb16, 1536, 8192, 1536, 512, 3);
            attn_mfma<64, 64, false><<<1024, 64, 0, stream>>>(
                Rb16, 1536, Rb16 + 512, 1536, Rb16 + 1024, 1536,
                Mb16 + (size_t)c * 8192 * 512, 512);
        }
        gemmT(Mb16, 512, WeOut + (size_t)i * 262144, 512, enc_out_b + (size_t)i * 512,
              nullptr, Rb16, 512, 32768, 512, 512, 3);
        ln_bf16<true, false><<<8192, 256, 0, stream>>>(Xb, Rb16,
            enc_ln1_g + (size_t)i * 512, enc_ln1_b + (size_t)i * 512, Xb, nullptr, 32768);
        for (int s = 0; s < 4; ++s) {
            gemmT(Xb + (size_t)s * 8192 * 512, 512, WeFf1 + (size_t)i * 1048576, 512,
                  enc_ff1_b + (size_t)i * 2048, nullptr, Mb16, 2048, 8192, 2048, 512, 2);
            gemmT64(Mb16, 2048, WeFf2 + (size_t)i * 1048576, 2048,
                    enc_ff2_b + (size_t)i * 512, nullptr, Rb16 + (size_t)s * 8192 * 512, 512,
                    8192, 512, 2048, 3);
        }
        ln_bf16<true, false><<<8192, 256, 0, stream>>>(Xb, Rb16,
            enc_ln2_g + (size_t)i * 512, enc_ln2_b + (size_t)i * 512, Xb, nullptr, 32768);
    }
    ln_bf16<false, false><<<8192, 256, 0, stream>>>(Xb, nullptr, enc_fn_g, enc_fn_b,
                                                    Xb, nullptr, 32768);
    // Xb is now MEMb

    // ---- decoder weights -> W ----
    __bf16* WdSaQkv = Wb + 0;
    __bf16* WdSaOut = Wb + 3145728;
    __bf16* WdCaQkv = Wb + 4194304;
    __bf16* WdCaOut = Wb + 7340032;
    __bf16* WdFf1   = Wb + 8388608;
    __bf16* WdFf2   = Wb + 12582912;
    tw(dec_sa_qkv_w, WdSaQkv, 512, 1536);
    tw(dec_sa_out_w, WdSaOut, 512, 512);
    tw(dec_ca_qkv_w, WdCaQkv, 512, 1536);
    tw(dec_ca_out_w, WdCaOut, 512, 512);
    tw(dec_ff1_w,    WdFf1,   512, 2048);
    tw(dec_ff2_w,    WdFf2,   2048, 512);

    // ================= decoder (full batch, 16384 rows) =================
    __bf16* ObD  = Mb16;
    __bf16* QbC  = Mb16;
    __bf16* ObCA = (__bf16*)(Mf + 2097152);
    for (int i = 0; i < NLAYER; ++i) {
        for (int c = 0; c < 2; ++c) {
            gemmT(Yb + (size_t)c * 8192 * 512, 512, WdSaQkv + (size_t)i * 786432, 512,
                  dec_sa_qkv_b + (size_t)i * 1536, nullptr, Rb16, 1536, 8192, 1536, 512, 3);
            attn_mfma<32, 32, true><<<2048, 64, 0, stream>>>(
                Rb16, 1536, Rb16 + 512, 1536, Rb16 + 1024, 1536,
                ObD + (size_t)c * 8192 * 512, 512);
        }
        gemmT64(ObD, 512, WdSaOut + (size_t)i * 262144, 512, dec_sa_out_b + (size_t)i * 512,
                nullptr, Rb16, 512, 16384, 512, 512, 3);
        ln_bf16<true, false><<<4096, 256, 0, stream>>>(Yb, Rb16,
            dec_ln1_g + (size_t)i * 512, dec_ln1_b + (size_t)i * 512, Yb, nullptr, 16384);
        for (int c = 0; c < 2; ++c) {
            gemmT64(Yb + (size_t)c * 8192 * 512, 512, WdCaQkv + (size_t)i * 786432, 512,
                    dec_ca_qkv_b + (size_t)i * 1536, nullptr, QbC, 512, 8192, 512, 512, 3);
            gemmT(Xb + (size_t)c * 16384 * 512, 512, WdCaQkv + (size_t)i * 786432 + 262144, 512,
                  dec_ca_qkv_b + (size_t)i * 1536 + 512, nullptr, Rb16, 1024, 16384, 1024, 512, 3);
            attn_mfma<32, 64, false><<<2048, 64, 0, stream>>>(
                QbC, 512, Rb16, 1024, Rb16 + 512, 1024,
                ObCA + (size_t)c * 8192 * 512, 512);
        }
        gemmT64(ObCA, 512, WdCaOut + (size_t)i * 262144, 512, dec_ca_out_b + (size_t)i * 512,
                nullptr, Rb16, 512, 16384, 512, 512, 3);
        ln_bf16<true, false><<<4096, 256, 0, stream>>>(Yb, Rb16,
            dec_ln2_g + (size_t)i * 512, dec_ln2_b + (size_t)i * 512, Yb, nullptr, 16384);
        for (int s = 0; s < 2; ++s) {
            gemmT(Yb + (size_t)s * 8192 * 512, 512, WdFf1 + (size_t)i * 1048576, 512,
                  dec_ff1_b + (size_t)i * 2048, nullptr, Mb16, 2048, 8192, 2048, 512, 2);
            gemmT64(Mb16, 2048, WdFf2 + (size_t)i * 1048576, 2048,
                    dec_ff2_b + (size_t)i * 512, nullptr, Rb16 + (size_t)s * 8192 * 512, 512,
                    8192, 512, 2048, 3);
        }
        ln_bf16<true, false><<<4096, 256, 0, stream>>>(Yb, Rb16,
            dec_ln3_g + (size_t)i * 512, dec_ln3_b + (size_t)i * 512, Yb, nullptr, 16384);
    }
    // final decoder LN -> fp32 in R
    float* Yf = Rf;
    ln_bf16<false, true><<<4096, 256, 0, stream>>>(Yb, nullptr, dec_fn_g, dec_fn_b,
                                                   nullptr, Yf, 16384);

    // map to FEAT=64 (node-major), then permute to t-major
    gemm(Yf, 512, w_map, 64, b_map, F, 64, 16384, 64, 512, 0);
    float* Ft = Wf;                          // 1,048,576 f (W dead)
    permute_F<<<4096, 256, 0, stream>>>(F, Ft);

    // ================= spatial GATv2 (fp32, t-major) =================
    float* G  = Mf;
    float* Hb = Mf + 4194304;
    float* Ib = Wf + 1048576;
    gemm(Ft, 64, g1_wl, 256, g1_bl, G,  256, 16384, 256, 64, 0);
    gemm(Ft, 64, g1_wr, 256, g1_br, Hb, 256, 16384, 256, 64, 0);
    gatv2_kernel<false><<<16384, 256, 0, stream>>>(G, Hb, g1_att, g1_bias, off, eid, esrc, Ib, nullptr);
    gemm(Ib, 256, g2_wl, 256, g2_bl, G,  256, 16384, 256, 256, 0);
    gemm(Ib, 256, g2_wr, 256, g2_br, Hb, 256, 16384, 256, 256, 0);
    gatv2_kernel<true><<<16384, 256, 0, stream>>>(G, Hb, g2_att, g2_bias, off, eid, esrc,
                                                  nullptr, (float*)d_out);
}